// Round 9
// baseline (5261.157 us; speedup 1.0000x reference)
//
#include <hip/hip_runtime.h>
#include <cstdint>
#include <cstddef>

#define NN 6890
#define NA 8
#define KC 15
#define ND 544
#define MR (NA * NN)                 // 55120
#define DEG 16
#define NNZ (MR * DEG)
#define BN_EPS 1e-5f
#define NSB 862                      // spmm blocks: 64 rows each
#define NRG 108                      // proj row-groups (64 rows)
#define PB (NA * NRG)                // 864 proj blocks

typedef unsigned int u32;
typedef _Float16 f16;
typedef __attribute__((ext_vector_type(8))) _Float16 f16x8;
typedef __attribute__((ext_vector_type(4))) float f32x4;
typedef __attribute__((ext_vector_type(4))) unsigned int u32x4;

union U4H8 { uint4 q; f16 h[8]; f16x8 v; };

__device__ __forceinline__ uint4 nt_load4(const uint4* p) {
    const u32x4 v = __builtin_nontemporal_load((const u32x4*)p);
    uint4 r; r.x = v.x; r.y = v.y; r.z = v.z; r.w = v.w; return r;
}
__device__ __forceinline__ void nt_store4(uint4 v, uint4* p) {
    u32x4 t; t.x = v.x; t.y = v.y; t.z = v.z; t.w = v.w;
    __builtin_nontemporal_store(t, (u32x4*)p);
}

__device__ __forceinline__ u32 packh(float a, float b) {
    union { f16 h[2]; u32 u; } c;
    c.h[0] = (f16)a; c.h[1] = (f16)b; return c.u;
}
__device__ __forceinline__ uint4 pack8h(const float* t) {
    uint4 m;
    m.x = packh(t[0], t[1]); m.y = packh(t[2], t[3]);
    m.z = packh(t[4], t[5]); m.w = packh(t[6], t[7]);
    return m;
}
__device__ __forceinline__ void acc8h(float* s, float v, uint4 g) {
    U4H8 c; c.q = g;
    #pragma unroll
    for (int i = 0; i < 8; ++i) s[i] += v * (float)c.h[i];
}

// ---------------- prep: pack cols(u16)+vals(f16), 16B per 4 nnz ----------------
__global__ __launch_bounds__(256)
void prep_cv_kernel(const int* __restrict__ cols, const float* __restrict__ vals,
                    uint4* __restrict__ cvq)
{
    const int q = blockIdx.x * 256 + threadIdx.x;
    if (q >= NNZ / 4) return;
    const int4   c = ((const int4*)cols)[q];
    const float4 v = ((const float4*)vals)[q];
    uint4 o;
    o.x = ((u32)c.x & 0xffffu) | ((u32)c.y << 16);
    o.y = ((u32)c.z & 0xffffu) | ((u32)c.w << 16);
    o.z = packh(v.x, v.y);
    o.w = packh(v.z, v.w);
    cvq[q] = o;
}

// ---------------- k=0: T0 = X chunk -> half-slabs (fp16) ----------------
template<int NH>
__global__ __launch_bounds__(256)
void tile_slab_kernel(const float* __restrict__ X, int C_in, int c0,
                      uint4* __restrict__ s0A, uint4* __restrict__ s0B)
{
    const int tid = threadIdx.x;
    const int r = blockIdx.x * 64 + (tid >> 2);
    const int j = tid & 3;
    if (r >= MR) return;
    const int n = r % NN;
    #pragma unroll
    for (int u = 0; u < NH; ++u) {
        const float* xp = X + (size_t)n * C_in + c0 + u * 32 + j * 8;
        const float4 t0 = *(const float4*)xp;
        const float4 t1 = *(const float4*)(xp + 4);
        float t[8] = { t0.x, t0.y, t0.z, t0.w, t1.x, t1.y, t1.z, t1.w };
        (u ? s0B : s0A)[(size_t)r * 4 + j] = pack8h(t);
    }
}

// ---------------- spmm: gather half-slab(k-1), carry k-2 (nt), write k (nt) ----
template<bool CHEB>
__device__ __forceinline__
void spmm_unit(int r, int j, const int* c, const float* v,
               const uint4* __restrict__ sp, const uint4* __restrict__ sc,
               uint4* __restrict__ sw)
{
    float s[8] = {0.f, 0.f, 0.f, 0.f, 0.f, 0.f, 0.f, 0.f};
    #pragma unroll
    for (int d = 0; d < DEG; ++d)
        acc8h(s, v[d], sp[(size_t)c[d] * 4 + j]);
    float t[8];
    if (CHEB) {
        U4H8 p; p.q = nt_load4(sc + (size_t)r * 4 + j);
        #pragma unroll
        for (int i = 0; i < 8; ++i) t[i] = 2.f * s[i] - (float)p.h[i];
    } else {
        #pragma unroll
        for (int i = 0; i < 8; ++i) t[i] = s[i];
    }
    nt_store4(pack8h(t), sw + (size_t)r * 4 + j);
}

template<int NH, bool CHEB>
__device__ __forceinline__
void spmm_body(const uint4* __restrict__ spA, const uint4* __restrict__ spB,
               const uint4* __restrict__ scA, const uint4* __restrict__ scB,
               uint4* __restrict__ swA, uint4* __restrict__ swB,
               const uint4* __restrict__ cvq)
{
    const int tid = threadIdx.x;
    const int r = blockIdx.x * 64 + (tid >> 2);
    const int j = tid & 3;
    if (r >= MR) return;
    int c[16]; float v[16];
    const uint4* cvp = cvq + (size_t)r * 4;
    #pragma unroll
    for (int q = 0; q < 4; ++q) {
        const uint4 cq = nt_load4(cvp + q);
        c[4 * q + 0] = cq.x & 0xffffu; c[4 * q + 1] = cq.x >> 16;
        c[4 * q + 2] = cq.y & 0xffffu; c[4 * q + 3] = cq.y >> 16;
        union { u32 u; f16 h[2]; } z, w_;
        z.u = cq.z; w_.u = cq.w;
        v[4 * q + 0] = (float)z.h[0]; v[4 * q + 1] = (float)z.h[1];
        v[4 * q + 2] = (float)w_.h[0]; v[4 * q + 3] = (float)w_.h[1];
    }
    spmm_unit<CHEB>(r, j, c, v, spA, scA, swA);      // phase A: ch 0-31
    if (NH == 2)
        spmm_unit<CHEB>(r, j, c, v, spB, scB, swB);  // phase B: ch 32-63
}

// ---------------- proj: part[a][n][h] (+)= T_k[a*NN+n][cc] * W_k[a*C+cc][h] -----
// A = fp16 half-slab rows (16B/lane). B = W as f16 hi+lo in LDS.
// mfma_f32_16x16x32_f16; C/D: col=l&15, row=(l>>4)*4+reg [m89-verified]
template<int NH, bool FIRSTP>
__device__ __forceinline__
void proj_body(int pb, const uint4* __restrict__ sA, const uint4* __restrict__ sB,
               const float* __restrict__ W, float* __restrict__ part,
               int C_in, int c0, int kproj, u32* WH, u32* WL)
{
    const int tid = threadIdx.x;
    const int l = tid & 63, w = tid >> 6;
    const int a = pb / NRG, rg = pb % NRG;
    const int rows0 = rg * 64;
    const int hi16 = l >> 4;
    const float* Wk = W + ((size_t)kproj * NA * C_in + (size_t)a * C_in + c0) * 64;

    for (int e = tid; e < NH * 1024; e += 256) {
        const int i2 = e & 3;
        const int ll = (e >> 2) & 63;
        const int nt = (e >> 8) & 3;
        const int h  = e >> 10;
        const int cc  = h * 32 + (ll >> 4) * 8 + 2 * i2;
        const int col = nt * 16 + (ll & 15);
        const float w0 = Wk[(size_t)cc * 64 + col];
        const float w1 = Wk[(size_t)(cc + 1) * 64 + col];
        const f16 h0 = (f16)w0, h1 = (f16)w1;
        union { f16 h[2]; u32 u; } ph, pl;
        ph.h[0] = h0; ph.h[1] = h1;
        pl.h[0] = (f16)(w0 - (float)h0); pl.h[1] = (f16)(w1 - (float)h1);
        WH[e] = ph.u; WL[e] = pl.u;
    }
    __syncthreads();

    const int arow = rows0 + w * 16 + (l & 15);
    const int arc  = arow < NN ? arow : NN - 1;
    const size_t abase = (size_t)(a * NN + arc) * 4;

    f32x4 acc[4];
    #pragma unroll
    for (int nt = 0; nt < 4; ++nt) {
        #pragma unroll
        for (int rr = 0; rr < 4; ++rr) {
            const int orow = rows0 + w * 16 + hi16 * 4 + rr;
            float vv = 0.f;
            if (!FIRSTP && orow < NN)
                vv = part[((size_t)a * NN + orow) * 64 + nt * 16 + (l & 15)];
            acc[nt][rr] = vv;
        }
    }
    #pragma unroll
    for (int h = 0; h < NH; ++h) {
        U4H8 af; af.q = (h == 0 ? sA : sB)[abase + hi16];
        #pragma unroll
        for (int nt = 0; nt < 4; ++nt) {
            const int be = ((h * 4 + nt) * 64 + l) * 4;
            U4H8 bh, bl;
            bh.q = *(const uint4*)&WH[be];
            bl.q = *(const uint4*)&WL[be];
            acc[nt] = __builtin_amdgcn_mfma_f32_16x16x32_f16(af.v, bh.v, acc[nt], 0, 0, 0);
            acc[nt] = __builtin_amdgcn_mfma_f32_16x16x32_f16(af.v, bl.v, acc[nt], 0, 0, 0);
        }
    }
    #pragma unroll
    for (int nt = 0; nt < 4; ++nt) {
        #pragma unroll
        for (int rr = 0; rr < 4; ++rr) {
            const int orow = rows0 + w * 16 + hi16 * 4 + rr;
            if (orow < NN)
                part[((size_t)a * NN + orow) * 64 + nt * 16 + (l & 15)] = acc[nt][rr];
        }
    }
}

// ---------------- combined step: spmm(k) + proj(k-1) ----------------
template<int NH, bool CHEB, bool FIRSTP>
__global__ __launch_bounds__(256)
void step_kernel(const uint4* __restrict__ spA, const uint4* __restrict__ spB,
                 const uint4* __restrict__ scA, const uint4* __restrict__ scB,
                 uint4* __restrict__ swA, uint4* __restrict__ swB,
                 const uint4* __restrict__ cvq,
                 const float* __restrict__ W, float* __restrict__ part,
                 int C_in, int c0, int kproj)
{
    __shared__ u32 WH[NH * 1024];
    __shared__ u32 WL[NH * 1024];
    if ((int)blockIdx.x < NSB)
        spmm_body<NH, CHEB>(spA, spB, scA, scB, swA, swB, cvq);
    else
        proj_body<NH, FIRSTP>((int)blockIdx.x - NSB, spA, spB, W, part, C_in, c0, kproj, WH, WL);
}

template<int NH>
__global__ __launch_bounds__(256)
void proj_only_kernel(const uint4* __restrict__ sA, const uint4* __restrict__ sB,
                      const float* __restrict__ W, float* __restrict__ part,
                      int C_in, int c0, int kproj)
{
    __shared__ u32 WH[NH * 1024];
    __shared__ u32 WL[NH * 1024];
    proj_body<NH, false>((int)blockIdx.x, sA, sB, W, part, C_in, c0, kproj, WH, WL);
}

// ---------------- BN helpers ----------------
__global__ void bn_reduce_kernel(const float* __restrict__ part, float* __restrict__ acc)
{
    const int e = blockIdx.x * blockDim.x + threadIdx.x;
    if (e >= NN * 64) return;
    float s = 0.f;
    #pragma unroll
    for (int a = 0; a < NA; ++a) s += part[(size_t)a * NN * 64 + e];
    acc[e] = s;
}

__global__ __launch_bounds__(256)
void bn_stats_kernel(const float* __restrict__ acc, const float* __restrict__ gamma,
                     const float* __restrict__ beta, float* __restrict__ bnp)
{
    const int h = blockIdx.x;
    float s = 0.f, sq = 0.f;
    for (int n = threadIdx.x; n < NN; n += 256) {
        const float v = acc[(size_t)n * 64 + h];
        s += v; sq += v * v;
    }
    __shared__ float ls[256], lq[256];
    ls[threadIdx.x] = s; lq[threadIdx.x] = sq;
    __syncthreads();
    for (int st = 128; st > 0; st >>= 1) {
        if (threadIdx.x < st) { ls[threadIdx.x] += ls[threadIdx.x + st]; lq[threadIdx.x] += lq[threadIdx.x + st]; }
        __syncthreads();
    }
    if (threadIdx.x == 0) {
        const float mean = ls[0] / (float)NN;
        const float var  = lq[0] / (float)NN - mean * mean;
        const float sc   = gamma[h] / sqrtf(var + BN_EPS);
        bnp[h]      = sc;
        bnp[64 + h] = beta[h] - mean * sc;
    }
}

__global__ void bn_apply_kernel(const float* __restrict__ acc, const float* __restrict__ bnp,
                                float* __restrict__ H)
{
    const int e = blockIdx.x * blockDim.x + threadIdx.x;
    if (e >= NN * 64) return;
    const int h = e & 63;
    const float v = acc[e] * bnp[h] + bnp[64 + h];
    H[e] = v > 0.f ? v : 0.f;
}

// ---------------- fc2: fp32 GEMM (+bias, relu), 4+4 split tiles ----------------
template<bool RELU>
__global__ __launch_bounds__(256)
void gemm_bias_kernel(const float* __restrict__ A, const float* __restrict__ B,
                      const float* __restrict__ bias, float* __restrict__ C,
                      int Mm, int Nn, int Kk)
{
    __shared__ float As[16][132];
    __shared__ float Bs[16][132];
    const int tx = threadIdx.x & 15, ty = threadIdx.x >> 4;
    const int m0 = blockIdx.y * 128, n0 = blockIdx.x * 128;
    const bool full = (m0 + 128 <= Mm) && (n0 + 128 <= Nn);
    float acc[8][8] = {};
    for (int k0 = 0; k0 < Kk; k0 += 16) {
        if (full) {
            #pragma unroll
            for (int e = threadIdx.x; e < 512; e += 256) {
                const int i = e >> 2, q = e & 3;
                const float4 a4 = *(const float4*)&A[(size_t)(m0 + i) * Kk + k0 + 4 * q];
                As[4 * q + 0][i] = a4.x; As[4 * q + 1][i] = a4.y;
                As[4 * q + 2][i] = a4.z; As[4 * q + 3][i] = a4.w;
            }
            #pragma unroll
            for (int e = threadIdx.x; e < 512; e += 256) {
                const int kk = e >> 5, q = e & 31;
                *(float4*)&Bs[kk][4 * q] = *(const float4*)&B[(size_t)(k0 + kk) * Nn + n0 + 4 * q];
            }
        } else {
            for (int e = threadIdx.x; e < 128 * 16; e += 256) {
                const int i = e >> 4, kk = e & 15;
                const int row = m0 + i;
                As[kk][i] = (row < Mm) ? A[(size_t)row * Kk + k0 + kk] : 0.f;
            }
            for (int e = threadIdx.x; e < 16 * 128; e += 256) {
                const int kk = e >> 7, jj = e & 127;
                const int col = n0 + jj;
                Bs[kk][jj] = (col < Nn) ? B[(size_t)(k0 + kk) * Nn + col] : 0.f;
            }
        }
        __syncthreads();
        #pragma unroll
        for (int kk = 0; kk < 16; ++kk) {
            float av[8], bv[8];
            *(float4*)&av[0] = *(const float4*)&As[kk][ty * 4];
            *(float4*)&av[4] = *(const float4*)&As[kk][64 + ty * 4];
            *(float4*)&bv[0] = *(const float4*)&Bs[kk][tx * 4];
            *(float4*)&bv[4] = *(const float4*)&Bs[kk][64 + tx * 4];
            #pragma unroll
            for (int i = 0; i < 8; ++i)
                #pragma unroll
                for (int jj = 0; jj < 8; ++jj)
                    acc[i][jj] += av[i] * bv[jj];
        }
        __syncthreads();
    }
    for (int i = 0; i < 8; ++i) {
        const int row = m0 + (i < 4 ? ty * 4 + i : 64 + ty * 4 + (i - 4));
        if (row >= Mm) continue;
        for (int jj = 0; jj < 8; ++jj) {
            const int col = n0 + (jj < 4 ? tx * 4 + jj : 64 + tx * 4 + (jj - 4));
            if (col >= Nn) continue;
            float v = acc[i][jj] + bias[col];
            if (RELU) v = fmaxf(v, 0.f);
            C[(size_t)row * Nn + col] = v;
        }
    }
}

// ---------------- prep: fc3_w -> transposed f16 hi/lo [col][k] ----------------
__global__ __launch_bounds__(256)
void w3_split_kernel(const float* __restrict__ W, f16* __restrict__ Wh, f16* __restrict__ Wl)
{
    __shared__ float t[64][65];
    const int tid = threadIdx.x;
    const int n0 = blockIdx.x * 64, k0 = blockIdx.y * 64;
    for (int e = tid; e < 64 * 64; e += 256) {
        const int kk = e >> 6, nn = e & 63;
        const int gn = n0 + nn;
        t[kk][nn] = (gn < NN) ? W[(size_t)(k0 + kk) * NN + gn] : 0.f;
    }
    __syncthreads();
    for (int e = tid; e < 64 * 64; e += 256) {
        const int nn = e >> 6, kk = e & 63;
        const int gn = n0 + nn;
        if (gn < NN) {
            const float w = t[kk][nn];
            const f16 h = (f16)w;
            Wh[(size_t)gn * 256 + k0 + kk] = h;
            Wl[(size_t)gn * 256 + k0 + kk] = (f16)(w - (float)h);
        }
    }
}

__global__ __launch_bounds__(256)
void f2_split_kernel(const float* __restrict__ f2, f16* __restrict__ Ah, f16* __restrict__ Al)
{
    const int e = blockIdx.x * 256 + threadIdx.x;
    if (e >= NN * 256) return;
    const float v = f2[e];
    const f16 h = (f16)v;
    Ah[e] = h;
    Al[e] = (f16)(v - (float)h);
}

// ---------------- fc3: LDS-free f16-split MFMA GEMM (3 products) ----------------
__global__ __launch_bounds__(256)
void fc3_mfma_kernel(const f16* __restrict__ Ah, const f16* __restrict__ Al,
                     const f16* __restrict__ Bh, const f16* __restrict__ Bl,
                     const float* __restrict__ bias, float* __restrict__ C)
{
    const int tid = threadIdx.x, l = tid & 63, w = tid >> 6;
    const int wm = w >> 1, wn = w & 1, hi16 = l >> 4;
    const int m0 = blockIdx.y * 128, n0 = blockIdx.x * 128;

    const f16* aph[4]; const f16* apl[4];
    const f16* bph[4]; const f16* bpl[4];
    #pragma unroll
    for (int mf = 0; mf < 4; ++mf) {
        int row = m0 + wm * 64 + mf * 16 + (l & 15);
        if (row > NN - 1) row = NN - 1;
        aph[mf] = Ah + (size_t)row * 256 + hi16 * 8;
        apl[mf] = Al + (size_t)row * 256 + hi16 * 8;
    }
    #pragma unroll
    for (int nf = 0; nf < 4; ++nf) {
        int col = n0 + wn * 64 + nf * 16 + (l & 15);
        if (col > NN - 1) col = NN - 1;
        bph[nf] = Bh + (size_t)col * 256 + hi16 * 8;
        bpl[nf] = Bl + (size_t)col * 256 + hi16 * 8;
    }

    f32x4 acc[4][4];
    #pragma unroll
    for (int mf = 0; mf < 4; ++mf)
        #pragma unroll
        for (int nf = 0; nf < 4; ++nf)
            acc[mf][nf] = (f32x4){0.f, 0.f, 0.f, 0.f};

    for (int k0 = 0; k0 < 256; k0 += 32) {
        f16x8 ah[4], al[4], bh[4], bl[4];
        #pragma unroll
        for (int mf = 0; mf < 4; ++mf) {
            ah[mf] = *(const f16x8*)(aph[mf] + k0);
            al[mf] = *(const f16x8*)(apl[mf] + k0);
        }
        #pragma unroll
        for (int nf = 0; nf < 4; ++nf) {
            bh[nf] = *(const f16x8*)(bph[nf] + k0);
            bl[nf] = *(const f16x8*)(bpl[nf] + k0);
        }
        #pragma unroll
        for (int mf = 0; mf < 4; ++mf)
            #pragma unroll
            for (int nf = 0; nf < 4; ++nf) {
                acc[mf][nf] = __builtin_amdgcn_mfma_f32_16x16x32_f16(ah[mf], bh[nf], acc[mf][nf], 0, 0, 0);
                acc[mf][nf] = __builtin_amdgcn_mfma_f32_16x16x32_f16(ah[mf], bl[nf], acc[mf][nf], 0, 0, 0);
                acc[mf][nf] = __builtin_amdgcn_mfma_f32_16x16x32_f16(al[mf], bh[nf], acc[mf][nf], 0, 0, 0);
            }
    }

    #pragma unroll
    for (int mf = 0; mf < 4; ++mf) {
        #pragma unroll
        for (int nf = 0; nf < 4; ++nf) {
            const int col = n0 + wn * 64 + nf * 16 + (l & 15);
            if (col >= NN) continue;
            const float bv = bias[col];
            #pragma unroll
            for (int rr = 0; rr < 4; ++rr) {
                const int row = m0 + wm * 64 + mf * 16 + hi16 * 4 + rr;
                if (row < NN)
                    C[(size_t)row * NN + col] = acc[mf][nf][rr] + bv;
            }
        }
    }
}

// ---------------- chunk driver ----------------
template<int NH>
static void run_chunk(bool first, const float* X, int C_in, int c0,
                      const uint4* cvq, const float* W,
                      uint4* const su[3][2], float* part, hipStream_t stream)
{
    tile_slab_kernel<NH><<<NSB, 256, 0, stream>>>(X, C_in, c0, su[0][0], su[0][1]);
    if (first)
        step_kernel<NH, false, true ><<<NSB + PB, 256, 0, stream>>>(
            su[0][0], su[0][1], su[0][0], su[0][1], su[1][0], su[1][1],
            cvq, W, part, C_in, c0, 0);
    else
        step_kernel<NH, false, false><<<NSB + PB, 256, 0, stream>>>(
            su[0][0], su[0][1], su[0][0], su[0][1], su[1][0], su[1][1],
            cvq, W, part, C_in, c0, 0);
    for (int k = 2; k < KC; ++k) {
        const int p = (k - 1) % 3, c = (k - 2) % 3, n = k % 3;
        step_kernel<NH, true, false><<<NSB + PB, 256, 0, stream>>>(
            su[p][0], su[p][1], su[c][0], su[c][1], su[n][0], su[n][1],
            cvq, W, part, C_in, c0, k - 1);
    }
    const int lastp = (KC - 1) % 3;
    proj_only_kernel<NH><<<PB, 256, 0, stream>>>(su[lastp][0], su[lastp][1],
                                                 W, part, C_in, c0, KC - 1);
}

extern "C" void kernel_launch(void* const* d_in, const int* in_sizes, int n_in,
                              void* d_out, int out_size, void* d_ws, size_t ws_size,
                              hipStream_t stream)
{
    (void)in_sizes; (void)n_in; (void)out_size; (void)ws_size;
    const float* x     = (const float*)d_in[0];
    const int*   cols  = (const int*)  d_in[2];
    const float* vals  = (const float*)d_in[3];
    const float* W1    = (const float*)d_in[4];
    const float* Wc    = (const float*)d_in[5];
    const float* gamma = (const float*)d_in[7];
    const float* beta  = (const float*)d_in[8];
    const float* fc2w  = (const float*)d_in[9];
    const float* fc2b  = (const float*)d_in[10];
    const float* fc3w  = (const float*)d_in[11];
    const float* fc3b  = (const float*)d_in[12];

    const size_t MT  = (size_t)MR * 64;
    const size_t S32 = (size_t)MR * 4;           // uint4 per half-slab (3.53 MB)

    char* base = (char*)d_ws;
    size_t off = 0;
    uint4* cvq  = (uint4*)(base + off); off += (size_t)(NNZ / 4) * 16;   // 3.53 MB
    uint4* slabs = (uint4*)(base + off); off += 6 * S32 * 16;            // 21.2 MB
    float* part = (float*)(base + off); off += MT * 4;                   // 14.1 MB
    float* acc  = (float*)(base + off); off += (size_t)NN * 64 * 4;
    float* H    = (float*)(base + off); off += (size_t)NN * 64 * 4;
    float* f2   = (float*)(base + off); off += (size_t)NN * 256 * 4;
    f16* f2h    = (f16*)(base + off);   off += (size_t)NN * 256 * 2;
    f16* f2l    = (f16*)(base + off);   off += (size_t)NN * 256 * 2;
    f16* W3h    = (f16*)(base + off);   off += (size_t)NN * 256 * 2;
    f16* W3l    = (f16*)(base + off);   off += (size_t)NN * 256 * 2;
    float* bnp  = (float*)(base + off);

    uint4* su[3][2];
    for (int s = 0; s < 3; ++s)
        for (int u = 0; u < 2; ++u)
            su[s][u] = slabs + (size_t)(s * 2 + u) * S32;

    prep_cv_kernel<<<(NNZ / 4 + 255) / 256, 256, 0, stream>>>(cols, vals, cvq);
    w3_split_kernel<<<dim3(108, 4), 256, 0, stream>>>(fc3w, W3h, W3l);

    for (int li = 0; li < 6; ++li) {
        const int C_in = (li == 0) ? ND : 64;
        const float* X = (li == 0) ? x : H;
        const float* W = (li == 0) ? W1 : Wc + (size_t)(li - 1) * KC * (NA * 64) * 64;
        const int nfull = C_in / 64;
        for (int c = 0; c < nfull; ++c)
            run_chunk<2>(c == 0, X, C_in, c * 64, cvq, W, su, part, stream);
        if (C_in % 64)
            run_chunk<1>(false, X, C_in, nfull * 64, cvq, W, su, part, stream);

        bn_reduce_kernel<<<(NN * 64 + 255) / 256, 256, 0, stream>>>(part, acc);
        bn_stats_kernel<<<64, 256, 0, stream>>>(acc, gamma + li * 64, beta + li * 64, bnp);
        bn_apply_kernel<<<(NN * 64 + 255) / 256, 256, 0, stream>>>(acc, bnp, H);
    }

    gemm_bias_kernel<true><<<dim3(2, 54), 256, 0, stream>>>(H, fc2w, fc2b, f2, NN, 256, 64);
    f2_split_kernel<<<(NN * 256 + 255) / 256, 256, 0, stream>>>(f2, f2h, f2l);
    fc3_mfma_kernel<<<dim3(54, 54), 256, 0, stream>>>(f2h, f2l, W3h, W3l, fc3b, (float*)d_out);
}

// Round 10
// 4367.622 us; speedup vs baseline: 1.2046x; 1.2046x over previous
//
#include <hip/hip_runtime.h>
#include <cstdint>
#include <cstddef>

#define NN 6890
#define NA 8
#define KC 15
#define ND 544
#define MR (NA * NN)                 // 55120
#define DEG 16
#define NNZ (MR * DEG)
#define BN_EPS 1e-5f
#define NRG 108                      // proj row-groups (64 rows)
#define PB (NA * NRG)                // 864 proj blocks

typedef unsigned int u32;
typedef _Float16 f16;
typedef __attribute__((ext_vector_type(8))) _Float16 f16x8;
typedef __attribute__((ext_vector_type(4))) float f32x4;

union U4H8 { uint4 q; f16 h[8]; f16x8 v; };

__device__ __forceinline__ u32 packh(float a, float b) {
    union { f16 h[2]; u32 u; } c;
    c.h[0] = (f16)a; c.h[1] = (f16)b; return c.u;
}
__device__ __forceinline__ uint4 pack8h(const float* t) {
    uint4 m;
    m.x = packh(t[0], t[1]); m.y = packh(t[2], t[3]);
    m.z = packh(t[4], t[5]); m.w = packh(t[6], t[7]);
    return m;
}
__device__ __forceinline__ void acc8h(float* s, float v, uint4 g) {
    U4H8 c; c.q = g;
    #pragma unroll
    for (int i = 0; i < 8; ++i) s[i] += v * (float)c.h[i];
}

// ---------------- prep: pack cols(u16)+vals(f16), 16B per 4 nnz ----------------
__global__ __launch_bounds__(256)
void prep_cv_kernel(const int* __restrict__ cols, const float* __restrict__ vals,
                    uint4* __restrict__ cvq)
{
    const int q = blockIdx.x * 256 + threadIdx.x;
    if (q >= NNZ / 4) return;
    const int4   c = ((const int4*)cols)[q];
    const float4 v = ((const float4*)vals)[q];
    uint4 o;
    o.x = ((u32)c.x & 0xffffu) | ((u32)c.y << 16);
    o.y = ((u32)c.z & 0xffffu) | ((u32)c.w << 16);
    o.z = packh(v.x, v.y);
    o.w = packh(v.z, v.w);
    cvq[q] = o;
}

// ---------------- k=0: T0 = X chunk -> fp16 slab (full rows) ----------------
template<int CC>
__global__ __launch_bounds__(256)
void tile_slab_kernel(const float* __restrict__ X, int C_in, int c0,
                      uint4* __restrict__ slab0)
{
    constexpr int LPR = CC / 8;
    constexpr int RPB = 256 / LPR;
    const int tid = threadIdx.x;
    const int j = tid % LPR, rloc = tid / LPR;
    const int r = blockIdx.x * RPB + rloc;
    if (r >= MR) return;
    const int n = r % NN;
    const float* xp = X + (size_t)n * C_in + c0 + 8 * j;
    const float4 t0 = *(const float4*)xp;
    const float4 t1 = *(const float4*)(xp + 4);
    float t[8] = { t0.x, t0.y, t0.z, t0.w, t1.x, t1.y, t1.z, t1.w };
    slab0[(size_t)r * LPR + j] = pack8h(t);
}

// ---------------- spmm: gather slab(k-1) [128B rows], carry slab(k-2), write k --
template<int CC, bool CHEB>
__device__ __forceinline__
void spmm_body(const uint4* __restrict__ sp, const uint4* __restrict__ sc,
               uint4* __restrict__ sw, const uint4* __restrict__ cvq)
{
    constexpr int LPR = CC / 8;
    constexpr int RPB = 256 / LPR;
    const int tid = threadIdx.x;
    const int j = tid % LPR, rloc = tid / LPR;
    const int r = blockIdx.x * RPB + rloc;
    if (r >= MR) return;

    int c[16]; float v[16];
    const uint4* cvp = cvq + (size_t)r * 4;
    #pragma unroll
    for (int q = 0; q < 4; ++q) {
        const uint4 cq = cvp[q];
        c[4 * q + 0] = cq.x & 0xffffu; c[4 * q + 1] = cq.x >> 16;
        c[4 * q + 2] = cq.y & 0xffffu; c[4 * q + 3] = cq.y >> 16;
        union { u32 u; f16 h[2]; } z, w_;
        z.u = cq.z; w_.u = cq.w;
        v[4 * q + 0] = (float)z.h[0]; v[4 * q + 1] = (float)z.h[1];
        v[4 * q + 2] = (float)w_.h[0]; v[4 * q + 3] = (float)w_.h[1];
    }
    float s[8] = {0.f, 0.f, 0.f, 0.f, 0.f, 0.f, 0.f, 0.f};
    #pragma unroll
    for (int d = 0; d < DEG; ++d)
        acc8h(s, v[d], sp[(size_t)c[d] * LPR + j]);
    float t[8];
    if (CHEB) {
        U4H8 p; p.q = sc[(size_t)r * LPR + j];
        #pragma unroll
        for (int i = 0; i < 8; ++i) t[i] = 2.f * s[i] - (float)p.h[i];
    } else {
        #pragma unroll
        for (int i = 0; i < 8; ++i) t[i] = s[i];
    }
    sw[(size_t)r * LPR + j] = pack8h(t);
}

// ---------------- proj: part[a][n][h] (+)= T_k[a*NN+n][cc] * W_k[a*C+cc][h] -----
// A = fp16 slab rows (16B/lane). B = W as f16 hi+lo in LDS.
// mfma_f32_16x16x32_f16; C/D: col=l&15, row=(l>>4)*4+reg [m89-verified]
template<int CC, bool FIRSTP>
__device__ __forceinline__
void proj_body(int pb, const uint4* __restrict__ sl, const float* __restrict__ W,
               float* __restrict__ part, int C_in, int c0, int kproj,
               u32* WH, u32* WL)
{
    constexpr int CCH = CC / 32;
    constexpr int LPR = CC / 8;
    const int tid = threadIdx.x;
    const int l = tid & 63, w = tid >> 6;
    const int a = pb / NRG, rg = pb % NRG;
    const int rows0 = rg * 64;
    const int hi16 = l >> 4;
    const float* Wk = W + ((size_t)kproj * NA * C_in + (size_t)a * C_in + c0) * 64;

    for (int e = tid; e < CCH * 1024; e += 256) {
        const int i2 = e & 3;
        const int ll = (e >> 2) & 63;
        const int nt = (e >> 8) & 3;
        const int h  = e >> 10;
        const int cc  = h * 32 + (ll >> 4) * 8 + 2 * i2;
        const int col = nt * 16 + (ll & 15);
        const float w0 = Wk[(size_t)cc * 64 + col];
        const float w1 = Wk[(size_t)(cc + 1) * 64 + col];
        const f16 h0 = (f16)w0, h1 = (f16)w1;
        union { f16 h[2]; u32 u; } ph, pl;
        ph.h[0] = h0; ph.h[1] = h1;
        pl.h[0] = (f16)(w0 - (float)h0); pl.h[1] = (f16)(w1 - (float)h1);
        WH[e] = ph.u; WL[e] = pl.u;
    }
    __syncthreads();

    const int arow = rows0 + w * 16 + (l & 15);
    const int arc  = arow < NN ? arow : NN - 1;
    const size_t abase = (size_t)(a * NN + arc) * LPR;

    f32x4 acc[4];
    #pragma unroll
    for (int nt = 0; nt < 4; ++nt) {
        #pragma unroll
        for (int rr = 0; rr < 4; ++rr) {
            const int orow = rows0 + w * 16 + hi16 * 4 + rr;
            float vv = 0.f;
            if (!FIRSTP && orow < NN)
                vv = part[((size_t)a * NN + orow) * 64 + nt * 16 + (l & 15)];
            acc[nt][rr] = vv;
        }
    }
    #pragma unroll
    for (int h = 0; h < CCH; ++h) {
        U4H8 af; af.q = sl[abase + h * 4 + hi16];
        #pragma unroll
        for (int nt = 0; nt < 4; ++nt) {
            const int be = ((h * 4 + nt) * 64 + l) * 4;
            U4H8 bh, bl;
            bh.q = *(const uint4*)&WH[be];
            bl.q = *(const uint4*)&WL[be];
            acc[nt] = __builtin_amdgcn_mfma_f32_16x16x32_f16(af.v, bh.v, acc[nt], 0, 0, 0);
            acc[nt] = __builtin_amdgcn_mfma_f32_16x16x32_f16(af.v, bl.v, acc[nt], 0, 0, 0);
        }
    }
    #pragma unroll
    for (int nt = 0; nt < 4; ++nt) {
        #pragma unroll
        for (int rr = 0; rr < 4; ++rr) {
            const int orow = rows0 + w * 16 + hi16 * 4 + rr;
            if (orow < NN)
                part[((size_t)a * NN + orow) * 64 + nt * 16 + (l & 15)] = acc[nt][rr];
        }
    }
}

// ---------------- combined step: spmm(k) + proj(k-1) ----------------
template<int CC, bool CHEB, bool FIRSTP>
__global__ __launch_bounds__(256)
void step_kernel(const uint4* __restrict__ sp, const uint4* __restrict__ sc,
                 uint4* __restrict__ sw, const uint4* __restrict__ cvq,
                 const float* __restrict__ W, float* __restrict__ part,
                 int C_in, int c0, int kproj, int NB)
{
    constexpr int CCH = CC / 32;
    __shared__ u32 WH[CCH * 1024];
    __shared__ u32 WL[CCH * 1024];
    if ((int)blockIdx.x < NB)
        spmm_body<CC, CHEB>(sp, sc, sw, cvq);
    else
        proj_body<CC, FIRSTP>((int)blockIdx.x - NB, sp, W, part, C_in, c0, kproj, WH, WL);
}

template<int CC>
__global__ __launch_bounds__(256)
void proj_only_kernel(const uint4* __restrict__ sl, const float* __restrict__ W,
                      float* __restrict__ part, int C_in, int c0, int kproj)
{
    constexpr int CCH = CC / 32;
    __shared__ u32 WH[CCH * 1024];
    __shared__ u32 WL[CCH * 1024];
    proj_body<CC, false>((int)blockIdx.x, sl, W, part, C_in, c0, kproj, WH, WL);
}

// ---------------- BN helpers ----------------
__global__ void bn_reduce_kernel(const float* __restrict__ part, float* __restrict__ acc)
{
    const int e = blockIdx.x * blockDim.x + threadIdx.x;
    if (e >= NN * 64) return;
    float s = 0.f;
    #pragma unroll
    for (int a = 0; a < NA; ++a) s += part[(size_t)a * NN * 64 + e];
    acc[e] = s;
}

__global__ __launch_bounds__(256)
void bn_stats_kernel(const float* __restrict__ acc, const float* __restrict__ gamma,
                     const float* __restrict__ beta, float* __restrict__ bnp)
{
    const int h = blockIdx.x;
    float s = 0.f, sq = 0.f;
    for (int n = threadIdx.x; n < NN; n += 256) {
        const float v = acc[(size_t)n * 64 + h];
        s += v; sq += v * v;
    }
    __shared__ float ls[256], lq[256];
    ls[threadIdx.x] = s; lq[threadIdx.x] = sq;
    __syncthreads();
    for (int st = 128; st > 0; st >>= 1) {
        if (threadIdx.x < st) { ls[threadIdx.x] += ls[threadIdx.x + st]; lq[threadIdx.x] += lq[threadIdx.x + st]; }
        __syncthreads();
    }
    if (threadIdx.x == 0) {
        const float mean = ls[0] / (float)NN;
        const float var  = lq[0] / (float)NN - mean * mean;
        const float sc   = gamma[h] / sqrtf(var + BN_EPS);
        bnp[h]      = sc;
        bnp[64 + h] = beta[h] - mean * sc;
    }
}

__global__ void bn_apply_kernel(const float* __restrict__ acc, const float* __restrict__ bnp,
                                float* __restrict__ H)
{
    const int e = blockIdx.x * blockDim.x + threadIdx.x;
    if (e >= NN * 64) return;
    const int h = e & 63;
    const float v = acc[e] * bnp[h] + bnp[64 + h];
    H[e] = v > 0.f ? v : 0.f;
}

// ---------------- fc2: fp32 GEMM (+bias, relu), 4+4 split tiles ----------------
template<bool RELU>
__global__ __launch_bounds__(256)
void gemm_bias_kernel(const float* __restrict__ A, const float* __restrict__ B,
                      const float* __restrict__ bias, float* __restrict__ C,
                      int Mm, int Nn, int Kk)
{
    __shared__ float As[16][132];
    __shared__ float Bs[16][132];
    const int tx = threadIdx.x & 15, ty = threadIdx.x >> 4;
    const int m0 = blockIdx.y * 128, n0 = blockIdx.x * 128;
    const bool full = (m0 + 128 <= Mm) && (n0 + 128 <= Nn);
    float acc[8][8] = {};
    for (int k0 = 0; k0 < Kk; k0 += 16) {
        if (full) {
            #pragma unroll
            for (int e = threadIdx.x; e < 512; e += 256) {
                const int i = e >> 2, q = e & 3;
                const float4 a4 = *(const float4*)&A[(size_t)(m0 + i) * Kk + k0 + 4 * q];
                As[4 * q + 0][i] = a4.x; As[4 * q + 1][i] = a4.y;
                As[4 * q + 2][i] = a4.z; As[4 * q + 3][i] = a4.w;
            }
            #pragma unroll
            for (int e = threadIdx.x; e < 512; e += 256) {
                const int kk = e >> 5, q = e & 31;
                *(float4*)&Bs[kk][4 * q] = *(const float4*)&B[(size_t)(k0 + kk) * Nn + n0 + 4 * q];
            }
        } else {
            for (int e = threadIdx.x; e < 128 * 16; e += 256) {
                const int i = e >> 4, kk = e & 15;
                const int row = m0 + i;
                As[kk][i] = (row < Mm) ? A[(size_t)row * Kk + k0 + kk] : 0.f;
            }
            for (int e = threadIdx.x; e < 16 * 128; e += 256) {
                const int kk = e >> 7, jj = e & 127;
                const int col = n0 + jj;
                Bs[kk][jj] = (col < Nn) ? B[(size_t)(k0 + kk) * Nn + col] : 0.f;
            }
        }
        __syncthreads();
        #pragma unroll
        for (int kk = 0; kk < 16; ++kk) {
            float av[8], bv[8];
            *(float4*)&av[0] = *(const float4*)&As[kk][ty * 4];
            *(float4*)&av[4] = *(const float4*)&As[kk][64 + ty * 4];
            *(float4*)&bv[0] = *(const float4*)&Bs[kk][tx * 4];
            *(float4*)&bv[4] = *(const float4*)&Bs[kk][64 + tx * 4];
            #pragma unroll
            for (int i = 0; i < 8; ++i)
                #pragma unroll
                for (int jj = 0; jj < 8; ++jj)
                    acc[i][jj] += av[i] * bv[jj];
        }
        __syncthreads();
    }
    for (int i = 0; i < 8; ++i) {
        const int row = m0 + (i < 4 ? ty * 4 + i : 64 + ty * 4 + (i - 4));
        if (row >= Mm) continue;
        for (int jj = 0; jj < 8; ++jj) {
            const int col = n0 + (jj < 4 ? tx * 4 + jj : 64 + tx * 4 + (jj - 4));
            if (col >= Nn) continue;
            float v = acc[i][jj] + bias[col];
            if (RELU) v = fmaxf(v, 0.f);
            C[(size_t)row * Nn + col] = v;
        }
    }
}

// ---------------- prep: fc3_w -> transposed f16 hi/lo [col][k] ----------------
__global__ __launch_bounds__(256)
void w3_split_kernel(const float* __restrict__ W, f16* __restrict__ Wh, f16* __restrict__ Wl)
{
    __shared__ float t[64][65];
    const int tid = threadIdx.x;
    const int n0 = blockIdx.x * 64, k0 = blockIdx.y * 64;
    for (int e = tid; e < 64 * 64; e += 256) {
        const int kk = e >> 6, nn = e & 63;
        const int gn = n0 + nn;
        t[kk][nn] = (gn < NN) ? W[(size_t)(k0 + kk) * NN + gn] : 0.f;
    }
    __syncthreads();
    for (int e = tid; e < 64 * 64; e += 256) {
        const int nn = e >> 6, kk = e & 63;
        const int gn = n0 + nn;
        if (gn < NN) {
            const float w = t[kk][nn];
            const f16 h = (f16)w;
            Wh[(size_t)gn * 256 + k0 + kk] = h;
            Wl[(size_t)gn * 256 + k0 + kk] = (f16)(w - (float)h);
        }
    }
}

__global__ __launch_bounds__(256)
void f2_split_kernel(const float* __restrict__ f2, f16* __restrict__ Ah, f16* __restrict__ Al)
{
    const int e = blockIdx.x * 256 + threadIdx.x;
    if (e >= NN * 256) return;
    const float v = f2[e];
    const f16 h = (f16)v;
    Ah[e] = h;
    Al[e] = (f16)(v - (float)h);
}

// ---------------- fc3: LDS-free f16-split MFMA GEMM (3 products) ----------------
__global__ __launch_bounds__(256)
void fc3_mfma_kernel(const f16* __restrict__ Ah, const f16* __restrict__ Al,
                     const f16* __restrict__ Bh, const f16* __restrict__ Bl,
                     const float* __restrict__ bias, float* __restrict__ C)
{
    const int tid = threadIdx.x, l = tid & 63, w = tid >> 6;
    const int wm = w >> 1, wn = w & 1, hi16 = l >> 4;
    const int m0 = blockIdx.y * 128, n0 = blockIdx.x * 128;

    const f16* aph[4]; const f16* apl[4];
    const f16* bph[4]; const f16* bpl[4];
    #pragma unroll
    for (int mf = 0; mf < 4; ++mf) {
        int row = m0 + wm * 64 + mf * 16 + (l & 15);
        if (row > NN - 1) row = NN - 1;
        aph[mf] = Ah + (size_t)row * 256 + hi16 * 8;
        apl[mf] = Al + (size_t)row * 256 + hi16 * 8;
    }
    #pragma unroll
    for (int nf = 0; nf < 4; ++nf) {
        int col = n0 + wn * 64 + nf * 16 + (l & 15);
        if (col > NN - 1) col = NN - 1;
        bph[nf] = Bh + (size_t)col * 256 + hi16 * 8;
        bpl[nf] = Bl + (size_t)col * 256 + hi16 * 8;
    }

    f32x4 acc[4][4];
    #pragma unroll
    for (int mf = 0; mf < 4; ++mf)
        #pragma unroll
        for (int nf = 0; nf < 4; ++nf)
            acc[mf][nf] = (f32x4){0.f, 0.f, 0.f, 0.f};

    for (int k0 = 0; k0 < 256; k0 += 32) {
        f16x8 ah[4], al[4], bh[4], bl[4];
        #pragma unroll
        for (int mf = 0; mf < 4; ++mf) {
            ah[mf] = *(const f16x8*)(aph[mf] + k0);
            al[mf] = *(const f16x8*)(apl[mf] + k0);
        }
        #pragma unroll
        for (int nf = 0; nf < 4; ++nf) {
            bh[nf] = *(const f16x8*)(bph[nf] + k0);
            bl[nf] = *(const f16x8*)(bpl[nf] + k0);
        }
        #pragma unroll
        for (int mf = 0; mf < 4; ++mf)
            #pragma unroll
            for (int nf = 0; nf < 4; ++nf) {
                acc[mf][nf] = __builtin_amdgcn_mfma_f32_16x16x32_f16(ah[mf], bh[nf], acc[mf][nf], 0, 0, 0);
                acc[mf][nf] = __builtin_amdgcn_mfma_f32_16x16x32_f16(ah[mf], bl[nf], acc[mf][nf], 0, 0, 0);
                acc[mf][nf] = __builtin_amdgcn_mfma_f32_16x16x32_f16(al[mf], bh[nf], acc[mf][nf], 0, 0, 0);
            }
    }

    #pragma unroll
    for (int mf = 0; mf < 4; ++mf) {
        #pragma unroll
        for (int nf = 0; nf < 4; ++nf) {
            const int col = n0 + wn * 64 + nf * 16 + (l & 15);
            if (col >= NN) continue;
            const float bv = bias[col];
            #pragma unroll
            for (int rr = 0; rr < 4; ++rr) {
                const int row = m0 + wm * 64 + mf * 16 + hi16 * 4 + rr;
                if (row < NN)
                    C[(size_t)row * NN + col] = acc[mf][nf][rr] + bv;
            }
        }
    }
}

// ---------------- chunk driver ----------------
template<int CC>
static void run_chunk(bool first, const float* X, int C_in, int c0,
                      const uint4* cvq, const float* W,
                      uint4* const sl[3], float* part, hipStream_t stream)
{
    constexpr int RPB = 256 / (CC / 8);
    const int NB = (MR + RPB - 1) / RPB;

    tile_slab_kernel<CC><<<NB, 256, 0, stream>>>(X, C_in, c0, sl[0]);
    if (first)
        step_kernel<CC, false, true ><<<NB + PB, 256, 0, stream>>>(
            sl[0], sl[0], sl[1], cvq, W, part, C_in, c0, 0, NB);
    else
        step_kernel<CC, false, false><<<NB + PB, 256, 0, stream>>>(
            sl[0], sl[0], sl[1], cvq, W, part, C_in, c0, 0, NB);
    for (int k = 2; k < KC; ++k) {
        const int p = (k - 1) % 3, c = (k - 2) % 3, n = k % 3;
        step_kernel<CC, true, false><<<NB + PB, 256, 0, stream>>>(
            sl[p], sl[c], sl[n], cvq, W, part, C_in, c0, k - 1, NB);
    }
    proj_only_kernel<CC><<<PB, 256, 0, stream>>>(sl[(KC - 1) % 3], W, part, C_in, c0, KC - 1);
}

extern "C" void kernel_launch(void* const* d_in, const int* in_sizes, int n_in,
                              void* d_out, int out_size, void* d_ws, size_t ws_size,
                              hipStream_t stream)
{
    (void)in_sizes; (void)n_in; (void)out_size; (void)ws_size;
    const float* x     = (const float*)d_in[0];
    const int*   cols  = (const int*)  d_in[2];
    const float* vals  = (const float*)d_in[3];
    const float* W1    = (const float*)d_in[4];
    const float* Wc    = (const float*)d_in[5];
    const float* gamma = (const float*)d_in[7];
    const float* beta  = (const float*)d_in[8];
    const float* fc2w  = (const float*)d_in[9];
    const float* fc2b  = (const float*)d_in[10];
    const float* fc3w  = (const float*)d_in[11];
    const float* fc3b  = (const float*)d_in[12];

    const size_t MT   = (size_t)MR * 64;
    const size_t SLOT = (size_t)MR * 8;          // uint4 per full slab (7.06 MB)

    char* base = (char*)d_ws;
    size_t off = 0;
    uint4* cvq  = (uint4*)(base + off); off += (size_t)(NNZ / 4) * 16;   // 3.53 MB
    uint4* slabs = (uint4*)(base + off); off += 3 * SLOT * 16;           // 21.2 MB
    float* part = (float*)(base + off); off += MT * 4;                   // 14.1 MB
    float* acc  = (float*)(base + off); off += (size_t)NN * 64 * 4;
    float* H    = (float*)(base + off); off += (size_t)NN * 64 * 4;
    float* f2   = (float*)(base + off); off += (size_t)NN * 256 * 4;
    f16* f2h    = (f16*)(base + off);   off += (size_t)NN * 256 * 2;
    f16* f2l    = (f16*)(base + off);   off += (size_t)NN * 256 * 2;
    f16* W3h    = (f16*)(base + off);   off += (size_t)NN * 256 * 2;
    f16* W3l    = (f16*)(base + off);   off += (size_t)NN * 256 * 2;
    float* bnp  = (float*)(base + off);

    uint4* sl[3] = { slabs, slabs + SLOT, slabs + 2 * SLOT };

    prep_cv_kernel<<<(NNZ / 4 + 255) / 256, 256, 0, stream>>>(cols, vals, cvq);
    w3_split_kernel<<<dim3(108, 4), 256, 0, stream>>>(fc3w, W3h, W3l);

    for (int li = 0; li < 6; ++li) {
        const int C_in = (li == 0) ? ND : 64;
        const float* X = (li == 0) ? x : H;
        const float* W = (li == 0) ? W1 : Wc + (size_t)(li - 1) * KC * (NA * 64) * 64;
        const int nfull = C_in / 64;
        for (int c = 0; c < nfull; ++c)
            run_chunk<64>(c == 0, X, C_in, c * 64, cvq, W, sl, part, stream);
        if (C_in % 64)
            run_chunk<32>(false, X, C_in, nfull * 64, cvq, W, sl, part, stream);

        bn_reduce_kernel<<<(NN * 64 + 255) / 256, 256, 0, stream>>>(part, acc);
        bn_stats_kernel<<<64, 256, 0, stream>>>(acc, gamma + li * 64, beta + li * 64, bnp);
        bn_apply_kernel<<<(NN * 64 + 255) / 256, 256, 0, stream>>>(acc, bnp, H);
    }

    gemm_bias_kernel<true><<<dim3(2, 54), 256, 0, stream>>>(H, fc2w, fc2b, f2, NN, 256, 64);
    f2_split_kernel<<<(NN * 256 + 255) / 256, 256, 0, stream>>>(f2, f2h, f2l);
    fc3_mfma_kernel<<<dim3(54, 54), 256, 0, stream>>>(f2h, f2l, W3h, W3l, fc3b, (float*)d_out);
}

// Round 11
// 4292.141 us; speedup vs baseline: 1.2258x; 1.0176x over previous
//
#include <hip/hip_runtime.h>
#include <cstdint>
#include <cstddef>

#define NN 6890
#define NA 8
#define KC 15
#define ND 544
#define MR (NA * NN)                 // 55120
#define DEG 16
#define NNZ (MR * DEG)
#define BN_EPS 1e-5f
#define NRG 108                      // proj row-groups (64 rows)
#define PB (NA * NRG)                // 864 proj blocks

typedef unsigned int u32;
typedef _Float16 f16;
typedef __attribute__((ext_vector_type(8))) _Float16 f16x8;
typedef __attribute__((ext_vector_type(4))) float f32x4;

union U4H8 { uint4 q; f16 h[8]; f16x8 v; };

__device__ __forceinline__ u32 packh(float a, float b) {
    union { f16 h[2]; u32 u; } c;
    c.h[0] = (f16)a; c.h[1] = (f16)b; return c.u;
}
__device__ __forceinline__ uint4 pack8h(const float* t) {
    uint4 m;
    m.x = packh(t[0], t[1]); m.y = packh(t[2], t[3]);
    m.z = packh(t[4], t[5]); m.w = packh(t[6], t[7]);
    return m;
}
__device__ __forceinline__ void acc8h(float* s, float v, uint4 g) {
    U4H8 c; c.q = g;
    #pragma unroll
    for (int i = 0; i < 8; ++i) s[i] += v * (float)c.h[i];
}

// ---------------- prep: pack cols(u16)+vals(f16), 16B per 4 nnz ----------------
__global__ __launch_bounds__(256)
void prep_cv_kernel(const int* __restrict__ cols, const float* __restrict__ vals,
                    uint4* __restrict__ cvq)
{
    const int q = blockIdx.x * 256 + threadIdx.x;
    if (q >= NNZ / 4) return;
    const int4   c = ((const int4*)cols)[q];
    const float4 v = ((const float4*)vals)[q];
    uint4 o;
    o.x = ((u32)c.x & 0xffffu) | ((u32)c.y << 16);
    o.y = ((u32)c.z & 0xffffu) | ((u32)c.w << 16);
    o.z = packh(v.x, v.y);
    o.w = packh(v.z, v.w);
    cvq[q] = o;
}

// ---------------- k=0: T0 = X chunk -> fp16 slab (full rows) ----------------
template<int CC>
__global__ __launch_bounds__(256)
void tile_slab_kernel(const float* __restrict__ X, int C_in, int c0,
                      uint4* __restrict__ slab0)
{
    constexpr int LPR = CC / 8;
    constexpr int RPB = 256 / LPR;
    const int tid = threadIdx.x;
    const int j = tid % LPR, rloc = tid / LPR;
    const int r = blockIdx.x * RPB + rloc;
    if (r >= MR) return;
    const int n = r % NN;
    const float* xp = X + (size_t)n * C_in + c0 + 8 * j;
    const float4 t0 = *(const float4*)xp;
    const float4 t1 = *(const float4*)(xp + 4);
    float t[8] = { t0.x, t0.y, t0.z, t0.w, t1.x, t1.y, t1.z, t1.w };
    slab0[(size_t)r * LPR + j] = pack8h(t);
}

// ---------------- spmm: gather slab(k-1), carry slab(k-2), write slab(k) --------
template<int CC, bool CHEB>
__device__ __forceinline__
void spmm_body(const uint4* __restrict__ sp, const uint4* __restrict__ sc,
               uint4* __restrict__ sw, const uint4* __restrict__ cvq)
{
    constexpr int LPR = CC / 8;
    constexpr int RPB = 256 / LPR;
    const int tid = threadIdx.x;
    const int j = tid % LPR, rloc = tid / LPR;
    const int r = blockIdx.x * RPB + rloc;
    if (r >= MR) return;

    int c[16]; float v[16];
    const uint4* cvp = cvq + (size_t)r * 4;
    #pragma unroll
    for (int q = 0; q < 4; ++q) {
        const uint4 cq = cvp[q];
        c[4 * q + 0] = cq.x & 0xffffu; c[4 * q + 1] = cq.x >> 16;
        c[4 * q + 2] = cq.y & 0xffffu; c[4 * q + 3] = cq.y >> 16;
        union { u32 u; f16 h[2]; } z, w_;
        z.u = cq.z; w_.u = cq.w;
        v[4 * q + 0] = (float)z.h[0]; v[4 * q + 1] = (float)z.h[1];
        v[4 * q + 2] = (float)w_.h[0]; v[4 * q + 3] = (float)w_.h[1];
    }
    float s[8] = {0.f, 0.f, 0.f, 0.f, 0.f, 0.f, 0.f, 0.f};
    #pragma unroll
    for (int d = 0; d < DEG; ++d)
        acc8h(s, v[d], sp[(size_t)c[d] * LPR + j]);
    float t[8];
    if (CHEB) {
        U4H8 p; p.q = sc[(size_t)r * LPR + j];
        #pragma unroll
        for (int i = 0; i < 8; ++i) t[i] = 2.f * s[i] - (float)p.h[i];
    } else {
        #pragma unroll
        for (int i = 0; i < 8; ++i) t[i] = s[i];
    }
    sw[(size_t)r * LPR + j] = pack8h(t);
}

template<int CC, bool CHEB>
__global__ __launch_bounds__(256)
void spmm_only_kernel(const uint4* __restrict__ sp, const uint4* __restrict__ sc,
                      uint4* __restrict__ sw, const uint4* __restrict__ cvq)
{
    spmm_body<CC, CHEB>(sp, sc, sw, cvq);
}

// ---------------- proj: part (+)= sum_{p<NPROJ} T_{kbase+p} W_{kbase+p} --------
template<int CC, int NPROJ, bool FIRSTP>
__device__ __forceinline__
void proj_body(int pb, const uint4* __restrict__ s0, const uint4* __restrict__ s1,
               const float* __restrict__ W, float* __restrict__ part,
               int C_in, int c0, int kbase, u32* WH, u32* WL)
{
    constexpr int CCH = CC / 32;
    constexpr int LPR = CC / 8;
    const int tid = threadIdx.x;
    const int l = tid & 63, w = tid >> 6;
    const int a = pb / NRG, rg = pb % NRG;
    const int rows0 = rg * 64;
    const int hi16 = l >> 4;

    const int arow = rows0 + w * 16 + (l & 15);
    const int arc  = arow < NN ? arow : NN - 1;
    const size_t abase = (size_t)(a * NN + arc) * LPR;

    f32x4 acc[4];
    #pragma unroll
    for (int nt = 0; nt < 4; ++nt) {
        #pragma unroll
        for (int rr = 0; rr < 4; ++rr) {
            const int orow = rows0 + w * 16 + hi16 * 4 + rr;
            float vv = 0.f;
            if (!FIRSTP && orow < NN)
                vv = part[((size_t)a * NN + orow) * 64 + nt * 16 + (l & 15)];
            acc[nt][rr] = vv;
        }
    }

    #pragma unroll
    for (int p = 0; p < NPROJ; ++p) {
        const uint4* sl = (p == 0) ? s0 : s1;
        const float* Wk = W + ((size_t)(kbase + p) * NA * C_in + (size_t)a * C_in + c0) * 64;
        if (p) __syncthreads();
        for (int e = tid; e < CCH * 1024; e += 256) {
            const int i2 = e & 3;
            const int ll = (e >> 2) & 63;
            const int nt = (e >> 8) & 3;
            const int h  = e >> 10;
            const int cc  = h * 32 + (ll >> 4) * 8 + 2 * i2;
            const int col = nt * 16 + (ll & 15);
            const float w0 = Wk[(size_t)cc * 64 + col];
            const float w1 = Wk[(size_t)(cc + 1) * 64 + col];
            const f16 h0 = (f16)w0, h1 = (f16)w1;
            union { f16 h[2]; u32 u; } ph, pl;
            ph.h[0] = h0; ph.h[1] = h1;
            pl.h[0] = (f16)(w0 - (float)h0); pl.h[1] = (f16)(w1 - (float)h1);
            WH[e] = ph.u; WL[e] = pl.u;
        }
        __syncthreads();
        #pragma unroll
        for (int h = 0; h < CCH; ++h) {
            U4H8 af; af.q = sl[abase + h * 4 + hi16];
            #pragma unroll
            for (int nt = 0; nt < 4; ++nt) {
                const int be = ((h * 4 + nt) * 64 + l) * 4;
                U4H8 bh, bl;
                bh.q = *(const uint4*)&WH[be];
                bl.q = *(const uint4*)&WL[be];
                acc[nt] = __builtin_amdgcn_mfma_f32_16x16x32_f16(af.v, bh.v, acc[nt], 0, 0, 0);
                acc[nt] = __builtin_amdgcn_mfma_f32_16x16x32_f16(af.v, bl.v, acc[nt], 0, 0, 0);
            }
        }
    }

    #pragma unroll
    for (int nt = 0; nt < 4; ++nt) {
        #pragma unroll
        for (int rr = 0; rr < 4; ++rr) {
            const int orow = rows0 + w * 16 + hi16 * 4 + rr;
            if (orow < NN)
                part[((size_t)a * NN + orow) * 64 + nt * 16 + (l & 15)] = acc[nt][rr];
        }
    }
}

// ---------------- even step: spmm(k) + proj(k-2, k-1) ----------------
template<int CC, bool FIRSTP>
__global__ __launch_bounds__(256)
void step2_kernel(const uint4* __restrict__ sp, const uint4* __restrict__ sc,
                  uint4* __restrict__ sw, const uint4* __restrict__ cvq,
                  const float* __restrict__ W, float* __restrict__ part,
                  int C_in, int c0, int kbase, int NB)
{
    constexpr int CCH = CC / 32;
    __shared__ u32 WH[CCH * 1024];
    __shared__ u32 WL[CCH * 1024];
    if ((int)blockIdx.x < NB)
        spmm_body<CC, true>(sp, sc, sw, cvq);
    else
        proj_body<CC, 2, FIRSTP>((int)blockIdx.x - NB, sc, sp, W, part, C_in, c0, kbase, WH, WL);
}

template<int CC>
__global__ __launch_bounds__(256)
void proj_final_kernel(const uint4* __restrict__ sl, const float* __restrict__ W,
                       float* __restrict__ part, int C_in, int c0, int kproj)
{
    constexpr int CCH = CC / 32;
    __shared__ u32 WH[CCH * 1024];
    __shared__ u32 WL[CCH * 1024];
    proj_body<CC, 1, false>((int)blockIdx.x, sl, sl, W, part, C_in, c0, kproj, WH, WL);
}

// ---------------- BN helpers ----------------
__global__ void bn_reduce_kernel(const float* __restrict__ part, float* __restrict__ acc)
{
    const int e = blockIdx.x * blockDim.x + threadIdx.x;
    if (e >= NN * 64) return;
    float s = 0.f;
    #pragma unroll
    for (int a = 0; a < NA; ++a) s += part[(size_t)a * NN * 64 + e];
    acc[e] = s;
}

__global__ __launch_bounds__(256)
void bn_stats_kernel(const float* __restrict__ acc, const float* __restrict__ gamma,
                     const float* __restrict__ beta, float* __restrict__ bnp)
{
    const int h = blockIdx.x;
    float s = 0.f, sq = 0.f;
    for (int n = threadIdx.x; n < NN; n += 256) {
        const float v = acc[(size_t)n * 64 + h];
        s += v; sq += v * v;
    }
    __shared__ float ls[256], lq[256];
    ls[threadIdx.x] = s; lq[threadIdx.x] = sq;
    __syncthreads();
    for (int st = 128; st > 0; st >>= 1) {
        if (threadIdx.x < st) { ls[threadIdx.x] += ls[threadIdx.x + st]; lq[threadIdx.x] += lq[threadIdx.x + st]; }
        __syncthreads();
    }
    if (threadIdx.x == 0) {
        const float mean = ls[0] / (float)NN;
        const float var  = lq[0] / (float)NN - mean * mean;
        const float sc   = gamma[h] / sqrtf(var + BN_EPS);
        bnp[h]      = sc;
        bnp[64 + h] = beta[h] - mean * sc;
    }
}

__global__ void bn_apply_kernel(const float* __restrict__ acc, const float* __restrict__ bnp,
                                float* __restrict__ H)
{
    const int e = blockIdx.x * blockDim.x + threadIdx.x;
    if (e >= NN * 64) return;
    const int h = e & 63;
    const float v = acc[e] * bnp[h] + bnp[64 + h];
    H[e] = v > 0.f ? v : 0.f;
}

// ---------------- fc2: fp32 GEMM (+bias, relu), 4+4 split tiles ----------------
template<bool RELU>
__global__ __launch_bounds__(256)
void gemm_bias_kernel(const float* __restrict__ A, const float* __restrict__ B,
                      const float* __restrict__ bias, float* __restrict__ C,
                      int Mm, int Nn, int Kk)
{
    __shared__ float As[16][132];
    __shared__ float Bs[16][132];
    const int tx = threadIdx.x & 15, ty = threadIdx.x >> 4;
    const int m0 = blockIdx.y * 128, n0 = blockIdx.x * 128;
    const bool full = (m0 + 128 <= Mm) && (n0 + 128 <= Nn);
    float acc[8][8] = {};
    for (int k0 = 0; k0 < Kk; k0 += 16) {
        if (full) {
            #pragma unroll
            for (int e = threadIdx.x; e < 512; e += 256) {
                const int i = e >> 2, q = e & 3;
                const float4 a4 = *(const float4*)&A[(size_t)(m0 + i) * Kk + k0 + 4 * q];
                As[4 * q + 0][i] = a4.x; As[4 * q + 1][i] = a4.y;
                As[4 * q + 2][i] = a4.z; As[4 * q + 3][i] = a4.w;
            }
            #pragma unroll
            for (int e = threadIdx.x; e < 512; e += 256) {
                const int kk = e >> 5, q = e & 31;
                *(float4*)&Bs[kk][4 * q] = *(const float4*)&B[(size_t)(k0 + kk) * Nn + n0 + 4 * q];
            }
        } else {
            for (int e = threadIdx.x; e < 128 * 16; e += 256) {
                const int i = e >> 4, kk = e & 15;
                const int row = m0 + i;
                As[kk][i] = (row < Mm) ? A[(size_t)row * Kk + k0 + kk] : 0.f;
            }
            for (int e = threadIdx.x; e < 16 * 128; e += 256) {
                const int kk = e >> 7, jj = e & 127;
                const int col = n0 + jj;
                Bs[kk][jj] = (col < Nn) ? B[(size_t)(k0 + kk) * Nn + col] : 0.f;
            }
        }
        __syncthreads();
        #pragma unroll
        for (int kk = 0; kk < 16; ++kk) {
            float av[8], bv[8];
            *(float4*)&av[0] = *(const float4*)&As[kk][ty * 4];
            *(float4*)&av[4] = *(const float4*)&As[kk][64 + ty * 4];
            *(float4*)&bv[0] = *(const float4*)&Bs[kk][tx * 4];
            *(float4*)&bv[4] = *(const float4*)&Bs[kk][64 + tx * 4];
            #pragma unroll
            for (int i = 0; i < 8; ++i)
                #pragma unroll
                for (int jj = 0; jj < 8; ++jj)
                    acc[i][jj] += av[i] * bv[jj];
        }
        __syncthreads();
    }
    for (int i = 0; i < 8; ++i) {
        const int row = m0 + (i < 4 ? ty * 4 + i : 64 + ty * 4 + (i - 4));
        if (row >= Mm) continue;
        for (int jj = 0; jj < 8; ++jj) {
            const int col = n0 + (jj < 4 ? tx * 4 + jj : 64 + tx * 4 + (jj - 4));
            if (col >= Nn) continue;
            float v = acc[i][jj] + bias[col];
            if (RELU) v = fmaxf(v, 0.f);
            C[(size_t)row * Nn + col] = v;
        }
    }
}

// ---- prep: fc3_w -> transposed f16 hi/lo, K-MAJOR [k/8][col][8] ----
__global__ __launch_bounds__(256)
void w3_split_kernel(const float* __restrict__ W, f16* __restrict__ Wh, f16* __restrict__ Wl)
{
    __shared__ float t[64][65];
    const int tid = threadIdx.x;
    const int n0 = blockIdx.x * 64, k0 = blockIdx.y * 64;
    for (int e = tid; e < 64 * 64; e += 256) {
        const int kk = e >> 6, nn = e & 63;
        const int gn = n0 + nn;
        t[kk][nn] = (gn < NN) ? W[(size_t)(k0 + kk) * NN + gn] : 0.f;
    }
    __syncthreads();
    for (int e = tid; e < 64 * 8; e += 256) {
        const int nn = e >> 3, c8 = e & 7;            // local chunk
        const int gn = n0 + nn;
        if (gn >= NN) continue;
        const size_t ob = ((size_t)((k0 >> 3) + c8) * NN + gn) * 8;
        f16 vh[8], vl[8];
        #pragma unroll
        for (int i = 0; i < 8; ++i) {
            const float w = t[c8 * 8 + i][nn];
            const f16 h = (f16)w;
            vh[i] = h; vl[i] = (f16)(w - (float)h);
        }
        *(uint4*)&Wh[ob] = *(const uint4*)vh;
        *(uint4*)&Wl[ob] = *(const uint4*)vl;
    }
}

// ---- prep: f2 -> f16 hi/lo, K-MAJOR [k/8][row][8] ----
__global__ __launch_bounds__(256)
void f2_split_kernel(const float* __restrict__ f2, f16* __restrict__ Ah, f16* __restrict__ Al)
{
    const int row = blockIdx.x * 256 + threadIdx.x;
    const int c = blockIdx.y;                          // 0..31
    if (row >= NN) return;
    const float4 a0 = *(const float4*)&f2[(size_t)row * 256 + c * 8];
    const float4 a1 = *(const float4*)&f2[(size_t)row * 256 + c * 8 + 4];
    const float vv[8] = { a0.x, a0.y, a0.z, a0.w, a1.x, a1.y, a1.z, a1.w };
    f16 vh[8], vl[8];
    #pragma unroll
    for (int i = 0; i < 8; ++i) {
        const f16 h = (f16)vv[i];
        vh[i] = h; vl[i] = (f16)(vv[i] - (float)h);
    }
    const size_t ob = ((size_t)c * NN + row) * 8;
    *(uint4*)&Ah[ob] = *(const uint4*)vh;
    *(uint4*)&Al[ob] = *(const uint4*)vl;
}

// ---------------- fc3: k-major LDS-free f16-split MFMA GEMM (3 products) --------
__global__ __launch_bounds__(256)
void fc3_mfma_kernel(const f16* __restrict__ Ah, const f16* __restrict__ Al,
                     const f16* __restrict__ Bh, const f16* __restrict__ Bl,
                     const float* __restrict__ bias, float* __restrict__ C)
{
    const int tid = threadIdx.x, l = tid & 63, w = tid >> 6;
    const int wm = w >> 1, wn = w & 1, hi16 = l >> 4;
    const int m0 = blockIdx.y * 128, n0 = blockIdx.x * 128;

    size_t aoff[4], boff[4];
    #pragma unroll
    for (int mf = 0; mf < 4; ++mf) {
        int row = m0 + wm * 64 + mf * 16 + (l & 15);
        if (row > NN - 1) row = NN - 1;
        aoff[mf] = (size_t)row * 8;
    }
    #pragma unroll
    for (int nf = 0; nf < 4; ++nf) {
        int col = n0 + wn * 64 + nf * 16 + (l & 15);
        if (col > NN - 1) col = NN - 1;
        boff[nf] = (size_t)col * 8;
    }

    f32x4 acc[4][4];
    #pragma unroll
    for (int mf = 0; mf < 4; ++mf)
        #pragma unroll
        for (int nf = 0; nf < 4; ++nf)
            acc[mf][nf] = (f32x4){0.f, 0.f, 0.f, 0.f};

    for (int k0 = 0; k0 < 256; k0 += 32) {
        const size_t cb = (size_t)((k0 >> 3) + hi16) * NN * 8;
        f16x8 ah[4], al[4], bh[4], bl[4];
        #pragma unroll
        for (int mf = 0; mf < 4; ++mf) {
            ah[mf] = *(const f16x8*)(Ah + cb + aoff[mf]);
            al[mf] = *(const f16x8*)(Al + cb + aoff[mf]);
        }
        #pragma unroll
        for (int nf = 0; nf < 4; ++nf) {
            bh[nf] = *(const f16x8*)(Bh + cb + boff[nf]);
            bl[nf] = *(const f16x8*)(Bl + cb + boff[nf]);
        }
        #pragma unroll
        for (int mf = 0; mf < 4; ++mf)
            #pragma unroll
            for (int nf = 0; nf < 4; ++nf) {
                acc[mf][nf] = __builtin_amdgcn_mfma_f32_16x16x32_f16(ah[mf], bh[nf], acc[mf][nf], 0, 0, 0);
                acc[mf][nf] = __builtin_amdgcn_mfma_f32_16x16x32_f16(ah[mf], bl[nf], acc[mf][nf], 0, 0, 0);
                acc[mf][nf] = __builtin_amdgcn_mfma_f32_16x16x32_f16(al[mf], bh[nf], acc[mf][nf], 0, 0, 0);
            }
    }

    #pragma unroll
    for (int mf = 0; mf < 4; ++mf) {
        #pragma unroll
        for (int nf = 0; nf < 4; ++nf) {
            const int col = n0 + wn * 64 + nf * 16 + (l & 15);
            if (col >= NN) continue;
            const float bv = bias[col];
            #pragma unroll
            for (int rr = 0; rr < 4; ++rr) {
                const int row = m0 + wm * 64 + mf * 16 + hi16 * 4 + rr;
                if (row < NN)
                    C[(size_t)row * NN + col] = acc[mf][nf][rr] + bv;
            }
        }
    }
}

// ---------------- chunk driver (4-slot ring, proj every 2 k's) ----------------
template<int CC>
static void run_chunk(bool first, const float* X, int C_in, int c0,
                      const uint4* cvq, const float* W,
                      uint4* const sl[4], float* part, hipStream_t stream)
{
    constexpr int RPB = 256 / (CC / 8);
    const int NB = (MR + RPB - 1) / RPB;

    tile_slab_kernel<CC><<<NB, 256, 0, stream>>>(X, C_in, c0, sl[0]);
    spmm_only_kernel<CC, false><<<NB, 256, 0, stream>>>(sl[0], sl[0], sl[1], cvq);   // k=1
    for (int k = 2; k < KC; ++k) {
        const int p = (k - 1) & 3, c = (k - 2) & 3, n = k & 3;
        if (k & 1) {
            spmm_only_kernel<CC, true><<<NB, 256, 0, stream>>>(sl[p], sl[c], sl[n], cvq);
        } else {
            if (first && k == 2)
                step2_kernel<CC, true ><<<NB + PB, 256, 0, stream>>>(
                    sl[p], sl[c], sl[n], cvq, W, part, C_in, c0, k - 2, NB);
            else
                step2_kernel<CC, false><<<NB + PB, 256, 0, stream>>>(
                    sl[p], sl[c], sl[n], cvq, W, part, C_in, c0, k - 2, NB);
        }
    }
    proj_final_kernel<CC><<<PB, 256, 0, stream>>>(sl[(KC - 1) & 3], W, part, C_in, c0, KC - 1);
}

extern "C" void kernel_launch(void* const* d_in, const int* in_sizes, int n_in,
                              void* d_out, int out_size, void* d_ws, size_t ws_size,
                              hipStream_t stream)
{
    (void)in_sizes; (void)n_in; (void)out_size; (void)ws_size;
    const float* x     = (const float*)d_in[0];
    const int*   cols  = (const int*)  d_in[2];
    const float* vals  = (const float*)d_in[3];
    const float* W1    = (const float*)d_in[4];
    const float* Wc    = (const float*)d_in[5];
    const float* gamma = (const float*)d_in[7];
    const float* beta  = (const float*)d_in[8];
    const float* fc2w  = (const float*)d_in[9];
    const float* fc2b  = (const float*)d_in[10];
    const float* fc3w  = (const float*)d_in[11];
    const float* fc3b  = (const float*)d_in[12];

    const size_t MT   = (size_t)MR * 64;
    const size_t SLOT = (size_t)MR * 8;          // uint4 per full slab (7.06 MB)

    char* base = (char*)d_ws;
    size_t off = 0;
    uint4* cvq  = (uint4*)(base + off); off += (size_t)(NNZ / 4) * 16;   // 3.53 MB
    uint4* slabs = (uint4*)(base + off); off += 4 * SLOT * 16;           // 28.2 MB
    float* part = (float*)(base + off); off += MT * 4;                   // 14.1 MB
    float* acc  = (float*)(base + off); off += (size_t)NN * 64 * 4;
    float* H    = (float*)(base + off); off += (size_t)NN * 64 * 4;
    float* f2   = (float*)(base + off); off += (size_t)NN * 256 * 4;
    f16* f2h    = (f16*)(base + off);   off += (size_t)NN * 256 * 2;
    f16* f2l    = (f16*)(base + off);   off += (size_t)NN * 256 * 2;
    f16* W3h    = (f16*)(base + off);   off += (size_t)NN * 256 * 2;
    f16* W3l    = (f16*)(base + off);   off += (size_t)NN * 256 * 2;
    float* bnp  = (float*)(base + off);

    uint4* sl[4] = { slabs, slabs + SLOT, slabs + 2 * SLOT, slabs + 3 * SLOT };

    prep_cv_kernel<<<(NNZ / 4 + 255) / 256, 256, 0, stream>>>(cols, vals, cvq);
    w3_split_kernel<<<dim3(108, 4), 256, 0, stream>>>(fc3w, W3h, W3l);

    for (int li = 0; li < 6; ++li) {
        const int C_in = (li == 0) ? ND : 64;
        const float* X = (li == 0) ? x : H;
        const float* W = (li == 0) ? W1 : Wc + (size_t)(li - 1) * KC * (NA * 64) * 64;
        const int nfull = C_in / 64;
        for (int c = 0; c < nfull; ++c)
            run_chunk<64>(c == 0, X, C_in, c * 64, cvq, W, sl, part, stream);
        if (C_in % 64)
            run_chunk<32>(false, X, C_in, nfull * 64, cvq, W, sl, part, stream);

        bn_reduce_kernel<<<(NN * 64 + 255) / 256, 256, 0, stream>>>(part, acc);
        bn_stats_kernel<<<64, 256, 0, stream>>>(acc, gamma + li * 64, beta + li * 64, bnp);
        bn_apply_kernel<<<(NN * 64 + 255) / 256, 256, 0, stream>>>(acc, bnp, H);
    }

    gemm_bias_kernel<true><<<dim3(2, 54), 256, 0, stream>>>(H, fc2w, fc2b, f2, NN, 256, 64);
    f2_split_kernel<<<dim3(27, 32), 256, 0, stream>>>(f2, f2h, f2l);
    fc3_mfma_kernel<<<dim3(54, 54), 256, 0, stream>>>(f2h, f2l, W3h, W3l, fc3b, (float*)d_out);
}

// Round 12
// 4171.565 us; speedup vs baseline: 1.2612x; 1.0289x over previous
//
#include <hip/hip_runtime.h>
#include <cstdint>
#include <cstddef>

#define NN 6890
#define NA 8
#define KC 15
#define ND 544
#define MR (NA * NN)                 // 55120
#define DEG 16
#define NNZ (MR * DEG)
#define BN_EPS 1e-5f
#define NRG 108                      // proj row-groups (64 rows)
#define PB (NA * NRG)                // 864 proj blocks

typedef unsigned int u32;
typedef _Float16 f16;
typedef __attribute__((ext_vector_type(8))) _Float16 f16x8;
typedef __attribute__((ext_vector_type(4))) float f32x4;

union U4H8 { uint4 q; f16 h[8]; f16x8 v; };

__device__ __forceinline__ u32 packh(float a, float b) {
    union { f16 h[2]; u32 u; } c;
    c.h[0] = (f16)a; c.h[1] = (f16)b; return c.u;
}
__device__ __forceinline__ uint4 pack8h(const float* t) {
    uint4 m;
    m.x = packh(t[0], t[1]); m.y = packh(t[2], t[3]);
    m.z = packh(t[4], t[5]); m.w = packh(t[6], t[7]);
    return m;
}
__device__ __forceinline__ void acc8h(float* s, float v, uint4 g) {
    U4H8 c; c.q = g;
    #pragma unroll
    for (int i = 0; i < 8; ++i) s[i] += v * (float)c.h[i];
}

// ---------------- prep: pack cols(u16)+vals(f16), 16B per 4 nnz ----------------
__global__ __launch_bounds__(256)
void prep_cv_kernel(const int* __restrict__ cols, const float* __restrict__ vals,
                    uint4* __restrict__ cvq)
{
    const int q = blockIdx.x * 256 + threadIdx.x;
    if (q >= NNZ / 4) return;
    const int4   c = ((const int4*)cols)[q];
    const float4 v = ((const float4*)vals)[q];
    uint4 o;
    o.x = ((u32)c.x & 0xffffu) | ((u32)c.y << 16);
    o.y = ((u32)c.z & 0xffffu) | ((u32)c.w << 16);
    o.z = packh(v.x, v.y);
    o.w = packh(v.z, v.w);
    cvq[q] = o;
}

// ---------------- k=0: T0 = X channels [c0, c0+CC) -> fp16 slab ----------------
template<int CC>
__global__ __launch_bounds__(256)
void tile_slab_kernel(const float* __restrict__ X, int C_in, int c0,
                      uint4* __restrict__ slab0)
{
    constexpr int LPR = CC / 8;
    constexpr int RPB = 256 / LPR;
    const int tid = threadIdx.x;
    const int j = tid % LPR, rloc = tid / LPR;
    const int r = blockIdx.x * RPB + rloc;
    if (r >= MR) return;
    const int n = r % NN;
    const float* xp = X + (size_t)n * C_in + c0 + 8 * j;
    const float4 t0 = *(const float4*)xp;
    const float4 t1 = *(const float4*)(xp + 4);
    float t[8] = { t0.x, t0.y, t0.z, t0.w, t1.x, t1.y, t1.z, t1.w };
    slab0[(size_t)r * LPR + j] = pack8h(t);
}

// ---------------- spmm: gather slab(k-1), carry slab(k-2), write slab(k) --------
template<int CC, bool CHEB>
__device__ __forceinline__
void spmm_body(const uint4* __restrict__ sp, const uint4* __restrict__ sc,
               uint4* __restrict__ sw, const uint4* __restrict__ cvq,
               uint4* cvl)
{
    constexpr int LPR = CC / 8;
    constexpr int RPB = 256 / LPR;
    const int tid = threadIdx.x;
    const int j = tid % LPR, rloc = tid / LPR;
    const int r0 = blockIdx.x * RPB;
    const int nrow = (MR - r0) < RPB ? (MR - r0) : RPB;
    for (int e = tid; e < nrow * 4; e += 256)
        cvl[e] = cvq[(size_t)r0 * 4 + e];
    __syncthreads();
    const int r = r0 + rloc;
    if (r >= MR) return;

    int c[16]; float v[16];
    #pragma unroll
    for (int q = 0; q < 4; ++q) {
        const uint4 cq = cvl[rloc * 4 + q];
        c[4 * q + 0] = cq.x & 0xffffu; c[4 * q + 1] = cq.x >> 16;
        c[4 * q + 2] = cq.y & 0xffffu; c[4 * q + 3] = cq.y >> 16;
        union { u32 u; f16 h[2]; } z, w_;
        z.u = cq.z; w_.u = cq.w;
        v[4 * q + 0] = (float)z.h[0]; v[4 * q + 1] = (float)z.h[1];
        v[4 * q + 2] = (float)w_.h[0]; v[4 * q + 3] = (float)w_.h[1];
    }
    float s[8] = {0.f, 0.f, 0.f, 0.f, 0.f, 0.f, 0.f, 0.f};
    #pragma unroll
    for (int d = 0; d < DEG; ++d)
        acc8h(s, v[d], sp[(size_t)c[d] * LPR + j]);
    float t[8];
    if (CHEB) {
        U4H8 p; p.q = sc[(size_t)r * LPR + j];
        #pragma unroll
        for (int i = 0; i < 8; ++i) t[i] = 2.f * s[i] - (float)p.h[i];
    } else {
        #pragma unroll
        for (int i = 0; i < 8; ++i) t[i] = s[i];
    }
    sw[(size_t)r * LPR + j] = pack8h(t);
}

template<int CC, bool CHEB>
__global__ __launch_bounds__(256)
void spmm_only_kernel(const uint4* __restrict__ sp, const uint4* __restrict__ sc,
                      uint4* __restrict__ sw, const uint4* __restrict__ cvq)
{
    constexpr int RPB = 256 / (CC / 8);
    __shared__ uint4 cvl[RPB * 4];
    spmm_body<CC, CHEB>(sp, sc, sw, cvq, cvl);
}

// ---- proj: part (+)= sum_{p<NPROJ} sum_{slices s} T[.., s] W[kbase+p][c0+s*64+..] ----
// A = fp16 slab rows; B = W as f16 hi+lo staged per (p,s) in LDS (8KB+8KB).
// mfma_f32_16x16x32_f16; C/D: col=l&15, row=(l>>4)*4+reg [m89-verified]
template<int SCC, int NPROJ, bool FIRSTP>
__device__ __forceinline__
void proj_body(int pb, const uint4* __restrict__ s0, const uint4* __restrict__ s1,
               const float* __restrict__ W, float* __restrict__ part,
               int C_in, int c0, int kbase, u32* WH, u32* WL)
{
    constexpr int LPRF   = SCC / 8;                    // uint4 per slab row
    constexpr int SLICES = SCC >= 64 ? SCC / 64 : 1;
    constexpr int SCH    = SCC >= 64 ? 64 : SCC;       // channels per slice
    constexpr int CCH    = SCH / 32;                   // 2 or 1
    const int tid = threadIdx.x;
    const int l = tid & 63, w = tid >> 6;
    const int a = pb / NRG, rg = pb % NRG;
    const int rows0 = rg * 64;
    const int hi16 = l >> 4;

    const int arow = rows0 + w * 16 + (l & 15);
    const int arc  = arow < NN ? arow : NN - 1;
    const size_t abase = (size_t)(a * NN + arc) * LPRF;

    f32x4 acc[4];
    #pragma unroll
    for (int nt = 0; nt < 4; ++nt) {
        #pragma unroll
        for (int rr = 0; rr < 4; ++rr) {
            const int orow = rows0 + w * 16 + hi16 * 4 + rr;
            float vv = 0.f;
            if (!FIRSTP && orow < NN)
                vv = part[((size_t)a * NN + orow) * 64 + nt * 16 + (l & 15)];
            acc[nt][rr] = vv;
        }
    }

    #pragma unroll
    for (int p = 0; p < NPROJ; ++p) {
        const uint4* sl = (p == 0) ? s0 : s1;
        #pragma unroll
        for (int s = 0; s < SLICES; ++s) {
            const float* Wk = W + ((size_t)(kbase + p) * NA * C_in
                                   + (size_t)a * C_in + c0 + s * 64) * 64;
            if (p | s) __syncthreads();
            for (int e = tid; e < CCH * 1024; e += 256) {
                const int i2 = e & 3;
                const int ll = (e >> 2) & 63;
                const int nt = (e >> 8) & 3;
                const int h  = e >> 10;
                const int cc  = h * 32 + (ll >> 4) * 8 + 2 * i2;
                const int col = nt * 16 + (ll & 15);
                const float w0 = Wk[(size_t)cc * 64 + col];
                const float w1 = Wk[(size_t)(cc + 1) * 64 + col];
                const f16 h0 = (f16)w0, h1 = (f16)w1;
                union { f16 h[2]; u32 u; } ph, pl;
                ph.h[0] = h0; ph.h[1] = h1;
                pl.h[0] = (f16)(w0 - (float)h0); pl.h[1] = (f16)(w1 - (float)h1);
                WH[e] = ph.u; WL[e] = pl.u;
            }
            __syncthreads();
            #pragma unroll
            for (int h = 0; h < CCH; ++h) {
                U4H8 af; af.q = sl[abase + s * 8 + h * 4 + hi16];
                #pragma unroll
                for (int nt = 0; nt < 4; ++nt) {
                    const int be = ((h * 4 + nt) * 64 + l) * 4;
                    U4H8 bh, bl;
                    bh.q = *(const uint4*)&WH[be];
                    bl.q = *(const uint4*)&WL[be];
                    acc[nt] = __builtin_amdgcn_mfma_f32_16x16x32_f16(af.v, bh.v, acc[nt], 0, 0, 0);
                    acc[nt] = __builtin_amdgcn_mfma_f32_16x16x32_f16(af.v, bl.v, acc[nt], 0, 0, 0);
                }
            }
        }
    }

    #pragma unroll
    for (int nt = 0; nt < 4; ++nt) {
        #pragma unroll
        for (int rr = 0; rr < 4; ++rr) {
            const int orow = rows0 + w * 16 + hi16 * 4 + rr;
            if (orow < NN)
                part[((size_t)a * NN + orow) * 64 + nt * 16 + (l & 15)] = acc[nt][rr];
        }
    }
}

// ---------------- even step: spmm(k) + proj(k-2, k-1) ----------------
template<int CC, bool FIRSTP>
__global__ __launch_bounds__(256)
void step2_kernel(const uint4* __restrict__ sp, const uint4* __restrict__ sc,
                  uint4* __restrict__ sw, const uint4* __restrict__ cvq,
                  const float* __restrict__ W, float* __restrict__ part,
                  int C_in, int c0, int kbase, int NB)
{
    constexpr int RPB = 256 / (CC / 8);
    __shared__ uint4 cvl[RPB * 4];
    __shared__ u32 WH[2048];
    __shared__ u32 WL[2048];
    if ((int)blockIdx.x < NB)
        spmm_body<CC, true>(sp, sc, sw, cvq, cvl);
    else
        proj_body<CC, 2, FIRSTP>((int)blockIdx.x - NB, sc, sp, W, part, C_in, c0, kbase, WH, WL);
}

template<int CC>
__global__ __launch_bounds__(256)
void proj_final_kernel(const uint4* __restrict__ sl, const float* __restrict__ W,
                       float* __restrict__ part, int C_in, int c0, int kproj)
{
    __shared__ u32 WH[2048];
    __shared__ u32 WL[2048];
    proj_body<CC, 1, false>((int)blockIdx.x, sl, sl, W, part, C_in, c0, kproj, WH, WL);
}

// ---------------- BN helpers ----------------
__global__ void bn_reduce_kernel(const float* __restrict__ part, float* __restrict__ acc)
{
    const int e = blockIdx.x * blockDim.x + threadIdx.x;
    if (e >= NN * 64) return;
    float s = 0.f;
    #pragma unroll
    for (int a = 0; a < NA; ++a) s += part[(size_t)a * NN * 64 + e];
    acc[e] = s;
}

__global__ __launch_bounds__(256)
void bn_stats_kernel(const float* __restrict__ acc, const float* __restrict__ gamma,
                     const float* __restrict__ beta, float* __restrict__ bnp)
{
    const int h = blockIdx.x;
    float s = 0.f, sq = 0.f;
    for (int n = threadIdx.x; n < NN; n += 256) {
        const float v = acc[(size_t)n * 64 + h];
        s += v; sq += v * v;
    }
    __shared__ float ls[256], lq[256];
    ls[threadIdx.x] = s; lq[threadIdx.x] = sq;
    __syncthreads();
    for (int st = 128; st > 0; st >>= 1) {
        if (threadIdx.x < st) { ls[threadIdx.x] += ls[threadIdx.x + st]; lq[threadIdx.x] += lq[threadIdx.x + st]; }
        __syncthreads();
    }
    if (threadIdx.x == 0) {
        const float mean = ls[0] / (float)NN;
        const float var  = lq[0] / (float)NN - mean * mean;
        const float sc   = gamma[h] / sqrtf(var + BN_EPS);
        bnp[h]      = sc;
        bnp[64 + h] = beta[h] - mean * sc;
    }
}

__global__ void bn_apply_kernel(const float* __restrict__ acc, const float* __restrict__ bnp,
                                float* __restrict__ H)
{
    const int e = blockIdx.x * blockDim.x + threadIdx.x;
    if (e >= NN * 64) return;
    const int h = e & 63;
    const float v = acc[e] * bnp[h] + bnp[64 + h];
    H[e] = v > 0.f ? v : 0.f;
}

// ---------------- fc2: fp32 GEMM (+bias, relu), 4+4 split tiles ----------------
template<bool RELU>
__global__ __launch_bounds__(256)
void gemm_bias_kernel(const float* __restrict__ A, const float* __restrict__ B,
                      const float* __restrict__ bias, float* __restrict__ C,
                      int Mm, int Nn, int Kk)
{
    __shared__ float As[16][132];
    __shared__ float Bs[16][132];
    const int tx = threadIdx.x & 15, ty = threadIdx.x >> 4;
    const int m0 = blockIdx.y * 128, n0 = blockIdx.x * 128;
    const bool full = (m0 + 128 <= Mm) && (n0 + 128 <= Nn);
    float acc[8][8] = {};
    for (int k0 = 0; k0 < Kk; k0 += 16) {
        if (full) {
            #pragma unroll
            for (int e = threadIdx.x; e < 512; e += 256) {
                const int i = e >> 2, q = e & 3;
                const float4 a4 = *(const float4*)&A[(size_t)(m0 + i) * Kk + k0 + 4 * q];
                As[4 * q + 0][i] = a4.x; As[4 * q + 1][i] = a4.y;
                As[4 * q + 2][i] = a4.z; As[4 * q + 3][i] = a4.w;
            }
            #pragma unroll
            for (int e = threadIdx.x; e < 512; e += 256) {
                const int kk = e >> 5, q = e & 31;
                *(float4*)&Bs[kk][4 * q] = *(const float4*)&B[(size_t)(k0 + kk) * Nn + n0 + 4 * q];
            }
        } else {
            for (int e = threadIdx.x; e < 128 * 16; e += 256) {
                const int i = e >> 4, kk = e & 15;
                const int row = m0 + i;
                As[kk][i] = (row < Mm) ? A[(size_t)row * Kk + k0 + kk] : 0.f;
            }
            for (int e = threadIdx.x; e < 16 * 128; e += 256) {
                const int kk = e >> 7, jj = e & 127;
                const int col = n0 + jj;
                Bs[kk][jj] = (col < Nn) ? B[(size_t)(k0 + kk) * Nn + col] : 0.f;
            }
        }
        __syncthreads();
        #pragma unroll
        for (int kk = 0; kk < 16; ++kk) {
            float av[8], bv[8];
            *(float4*)&av[0] = *(const float4*)&As[kk][ty * 4];
            *(float4*)&av[4] = *(const float4*)&As[kk][64 + ty * 4];
            *(float4*)&bv[0] = *(const float4*)&Bs[kk][tx * 4];
            *(float4*)&bv[4] = *(const float4*)&Bs[kk][64 + tx * 4];
            #pragma unroll
            for (int i = 0; i < 8; ++i)
                #pragma unroll
                for (int jj = 0; jj < 8; ++jj)
                    acc[i][jj] += av[i] * bv[jj];
        }
        __syncthreads();
    }
    for (int i = 0; i < 8; ++i) {
        const int row = m0 + (i < 4 ? ty * 4 + i : 64 + ty * 4 + (i - 4));
        if (row >= Mm) continue;
        for (int jj = 0; jj < 8; ++jj) {
            const int col = n0 + (jj < 4 ? tx * 4 + jj : 64 + tx * 4 + (jj - 4));
            if (col >= Nn) continue;
            float v = acc[i][jj] + bias[col];
            if (RELU) v = fmaxf(v, 0.f);
            C[(size_t)row * Nn + col] = v;
        }
    }
}

// ---- prep: fc3_w -> transposed f16 hi/lo, K-MAJOR [k/8][col][8] ----
__global__ __launch_bounds__(256)
void w3_split_kernel(const float* __restrict__ W, f16* __restrict__ Wh, f16* __restrict__ Wl)
{
    __shared__ float t[64][65];
    const int tid = threadIdx.x;
    const int n0 = blockIdx.x * 64, k0 = blockIdx.y * 64;
    for (int e = tid; e < 64 * 64; e += 256) {
        const int kk = e >> 6, nn = e & 63;
        const int gn = n0 + nn;
        t[kk][nn] = (gn < NN) ? W[(size_t)(k0 + kk) * NN + gn] : 0.f;
    }
    __syncthreads();
    for (int e = tid; e < 64 * 8; e += 256) {
        const int nn = e >> 3, c8 = e & 7;
        const int gn = n0 + nn;
        if (gn >= NN) continue;
        const size_t ob = ((size_t)((k0 >> 3) + c8) * NN + gn) * 8;
        f16 vh[8], vl[8];
        #pragma unroll
        for (int i = 0; i < 8; ++i) {
            const float w = t[c8 * 8 + i][nn];
            const f16 h = (f16)w;
            vh[i] = h; vl[i] = (f16)(w - (float)h);
        }
        *(uint4*)&Wh[ob] = *(const uint4*)vh;
        *(uint4*)&Wl[ob] = *(const uint4*)vl;
    }
}

// ---- prep: f2 -> f16 hi/lo, K-MAJOR [k/8][row][8] ----
__global__ __launch_bounds__(256)
void f2_split_kernel(const float* __restrict__ f2, f16* __restrict__ Ah, f16* __restrict__ Al)
{
    const int row = blockIdx.x * 256 + threadIdx.x;
    const int c = blockIdx.y;                          // 0..31
    if (row >= NN) return;
    const float4 a0 = *(const float4*)&f2[(size_t)row * 256 + c * 8];
    const float4 a1 = *(const float4*)&f2[(size_t)row * 256 + c * 8 + 4];
    const float vv[8] = { a0.x, a0.y, a0.z, a0.w, a1.x, a1.y, a1.z, a1.w };
    f16 vh[8], vl[8];
    #pragma unroll
    for (int i = 0; i < 8; ++i) {
        const f16 h = (f16)vv[i];
        vh[i] = h; vl[i] = (f16)(vv[i] - (float)h);
    }
    const size_t ob = ((size_t)c * NN + row) * 8;
    *(uint4*)&Ah[ob] = *(const uint4*)vh;
    *(uint4*)&Al[ob] = *(const uint4*)vl;
}

// ---------------- fc3: k-major LDS-free f16-split MFMA GEMM (3 products) --------
__global__ __launch_bounds__(256)
void fc3_mfma_kernel(const f16* __restrict__ Ah, const f16* __restrict__ Al,
                     const f16* __restrict__ Bh, const f16* __restrict__ Bl,
                     const float* __restrict__ bias, float* __restrict__ C)
{
    const int tid = threadIdx.x, l = tid & 63, w = tid >> 6;
    const int wm = w >> 1, wn = w & 1, hi16 = l >> 4;
    const int m0 = blockIdx.y * 128, n0 = blockIdx.x * 128;

    size_t aoff[4], boff[4];
    #pragma unroll
    for (int mf = 0; mf < 4; ++mf) {
        int row = m0 + wm * 64 + mf * 16 + (l & 15);
        if (row > NN - 1) row = NN - 1;
        aoff[mf] = (size_t)row * 8;
    }
    #pragma unroll
    for (int nf = 0; nf < 4; ++nf) {
        int col = n0 + wn * 64 + nf * 16 + (l & 15);
        if (col > NN - 1) col = NN - 1;
        boff[nf] = (size_t)col * 8;
    }

    f32x4 acc[4][4];
    #pragma unroll
    for (int mf = 0; mf < 4; ++mf)
        #pragma unroll
        for (int nf = 0; nf < 4; ++nf)
            acc[mf][nf] = (f32x4){0.f, 0.f, 0.f, 0.f};

    for (int k0 = 0; k0 < 256; k0 += 32) {
        const size_t cb = (size_t)((k0 >> 3) + hi16) * NN * 8;
        f16x8 ah[4], al[4], bh[4], bl[4];
        #pragma unroll
        for (int mf = 0; mf < 4; ++mf) {
            ah[mf] = *(const f16x8*)(Ah + cb + aoff[mf]);
            al[mf] = *(const f16x8*)(Al + cb + aoff[mf]);
        }
        #pragma unroll
        for (int nf = 0; nf < 4; ++nf) {
            bh[nf] = *(const f16x8*)(Bh + cb + boff[nf]);
            bl[nf] = *(const f16x8*)(Bl + cb + boff[nf]);
        }
        #pragma unroll
        for (int mf = 0; mf < 4; ++mf)
            #pragma unroll
            for (int nf = 0; nf < 4; ++nf) {
                acc[mf][nf] = __builtin_amdgcn_mfma_f32_16x16x32_f16(ah[mf], bh[nf], acc[mf][nf], 0, 0, 0);
                acc[mf][nf] = __builtin_amdgcn_mfma_f32_16x16x32_f16(ah[mf], bl[nf], acc[mf][nf], 0, 0, 0);
                acc[mf][nf] = __builtin_amdgcn_mfma_f32_16x16x32_f16(al[mf], bh[nf], acc[mf][nf], 0, 0, 0);
            }
    }

    #pragma unroll
    for (int mf = 0; mf < 4; ++mf) {
        #pragma unroll
        for (int nf = 0; nf < 4; ++nf) {
            const int col = n0 + wn * 64 + nf * 16 + (l & 15);
            if (col >= NN) continue;
            const float bv = bias[col];
            #pragma unroll
            for (int rr = 0; rr < 4; ++rr) {
                const int row = m0 + wm * 64 + mf * 16 + hi16 * 4 + rr;
                if (row < NN)
                    C[(size_t)row * NN + col] = acc[mf][nf][rr] + bv;
            }
        }
    }
}

// ---------------- chunk driver (ring-3, proj every 2 k's) ----------------
template<int CC>
static void run_chunk(bool first, const float* X, int C_in, int c0,
                      const uint4* cvq, const float* W,
                      uint4* slabs, float* part, hipStream_t stream)
{
    constexpr int RPB = 256 / (CC / 8);
    const int NB = (MR + RPB - 1) / RPB;
    const size_t SLOT = (size_t)MR * (CC / 8);      // uint4 per slab
    uint4* sl[3] = { slabs, slabs + SLOT, slabs + 2 * SLOT };

    tile_slab_kernel<CC><<<NB, 256, 0, stream>>>(X, C_in, c0, sl[0]);
    spmm_only_kernel<CC, false><<<NB, 256, 0, stream>>>(sl[0], sl[0], sl[1], cvq);   // k=1
    for (int k = 2; k < KC; ++k) {
        const int p = (k - 1) % 3, c = (k - 2) % 3, n = k % 3;
        if (k & 1) {
            spmm_only_kernel<CC, true><<<NB, 256, 0, stream>>>(sl[p], sl[c], sl[n], cvq);
        } else {
            if (first && k == 2)
                step2_kernel<CC, true ><<<NB + PB, 256, 0, stream>>>(
                    sl[p], sl[c], sl[n], cvq, W, part, C_in, c0, k - 2, NB);
            else
                step2_kernel<CC, false><<<NB + PB, 256, 0, stream>>>(
                    sl[p], sl[c], sl[n], cvq, W, part, C_in, c0, k - 2, NB);
        }
    }
    proj_final_kernel<CC><<<PB, 256, 0, stream>>>(sl[(KC - 1) % 3], W, part, C_in, c0, KC - 1);
}

extern "C" void kernel_launch(void* const* d_in, const int* in_sizes, int n_in,
                              void* d_out, int out_size, void* d_ws, size_t ws_size,
                              hipStream_t stream)
{
    (void)in_sizes; (void)n_in; (void)out_size;
    const float* x     = (const float*)d_in[0];
    const int*   cols  = (const int*)  d_in[2];
    const float* vals  = (const float*)d_in[3];
    const float* W1    = (const float*)d_in[4];
    const float* Wc    = (const float*)d_in[5];
    const float* gamma = (const float*)d_in[7];
    const float* beta  = (const float*)d_in[8];
    const float* fc2w  = (const float*)d_in[9];
    const float* fc2b  = (const float*)d_in[10];
    const float* fc3w  = (const float*)d_in[11];
    const float* fc3b  = (const float*)d_in[12];

    const size_t MT = (size_t)MR * 64;
    // fixed (non-slab) footprint in bytes:
    const size_t FIXED = (size_t)(NNZ / 4) * 16          // cvq
                       + MT * 4                          // part
                       + (size_t)NN * 64 * 4 * 2         // acc, H
                       + (size_t)NN * 256 * 4            // f2
                       + (size_t)NN * 256 * 2 * 4        // f2h,f2l,W3h,W3l
                       + 1024;                           // bnp
    // slab ring bytes for a given L0 chunk width:
    const size_t ring256 = 3 * (size_t)MR * 512;
    const size_t ring128 = 3 * (size_t)MR * 256;
    const size_t ring64  = 3 * (size_t)MR * 128;
    int ccL0 = 64;
    size_t ring = ring64;
    if (ws_size >= FIXED + ring256)      { ccL0 = 256; ring = ring256; }
    else if (ws_size >= FIXED + ring128) { ccL0 = 128; ring = ring128; }

    char* base = (char*)d_ws;
    size_t off = 0;
    uint4* cvq  = (uint4*)(base + off); off += (size_t)(NNZ / 4) * 16;
    uint4* slabs = (uint4*)(base + off); off += ring;
    float* part = (float*)(base + off); off += MT * 4;
    float* acc  = (float*)(base + off); off += (size_t)NN * 64 * 4;
    float* H    = (float*)(base + off); off += (size_t)NN * 64 * 4;
    float* f2   = (float*)(base + off); off += (size_t)NN * 256 * 4;
    f16* f2h    = (f16*)(base + off);   off += (size_t)NN * 256 * 2;
    f16* f2l    = (f16*)(base + off);   off += (size_t)NN * 256 * 2;
    f16* W3h    = (f16*)(base + off);   off += (size_t)NN * 256 * 2;
    f16* W3l    = (f16*)(base + off);   off += (size_t)NN * 256 * 2;
    float* bnp  = (float*)(base + off);

    prep_cv_kernel<<<(NNZ / 4 + 255) / 256, 256, 0, stream>>>(cols, vals, cvq);
    w3_split_kernel<<<dim3(108, 4), 256, 0, stream>>>(fc3w, W3h, W3l);

    for (int li = 0; li < 6; ++li) {
        const int C_in = (li == 0) ? ND : 64;
        const float* X = (li == 0) ? x : H;
        const float* W = (li == 0) ? W1 : Wc + (size_t)(li - 1) * KC * (NA * 64) * 64;

        if (li == 0) {
            int c0 = 0;
            bool first = true;
            const int wide = ccL0;
            while (c0 + wide <= 512) {
                if (wide == 256)      run_chunk<256>(first, X, C_in, c0, cvq, W, slabs, part, stream);
                else if (wide == 128) run_chunk<128>(first, X, C_in, c0, cvq, W, slabs, part, stream);
                else                  run_chunk<64> (first, X, C_in, c0, cvq, W, slabs, part, stream);
                c0 += wide; first = false;
            }
            while (c0 + 64 <= ND) {     // remaining full 64-chunks (for 128/64 tiers, none for 256)
                run_chunk<64>(first, X, C_in, c0, cvq, W, slabs, part, stream);
                c0 += 64; first = false;
            }
            run_chunk<32>(false, X, C_in, c0, cvq, W, slabs, part, stream);   // 32-ch tail
        } else {
            run_chunk<64>(true, X, C_in, 0, cvq, W, slabs, part, stream);
        }

        bn_reduce_kernel<<<(NN * 64 + 255) / 256, 256, 0, stream>>>(part, acc);
        bn_stats_kernel<<<64, 256, 0, stream>>>(acc, gamma + li * 64, beta + li * 64, bnp);
        bn_apply_kernel<<<(NN * 64 + 255) / 256, 256, 0, stream>>>(acc, bnp, H);
    }

    gemm_bias_kernel<true><<<dim3(2, 54), 256, 0, stream>>>(H, fc2w, fc2b, f2, NN, 256, 64);
    f2_split_kernel<<<dim3(27, 32), 256, 0, stream>>>(f2, f2h, f2l);
    fc3_mfma_kernel<<<dim3(54, 54), 256, 0, stream>>>(f2h, f2l, W3h, W3l, fc3b, (float*)d_out);
}

// Round 13
// 4084.512 us; speedup vs baseline: 1.2881x; 1.0213x over previous
//
#include <hip/hip_runtime.h>
#include <cstdint>
#include <cstddef>

#define NN 6890
#define NA 8
#define KC 15
#define ND 544
#define MR (NA * NN)                 // 55120
#define DEG 16
#define NNZ (MR * DEG)
#define BN_EPS 1e-5f
#define NRG 108                      // proj row-groups (64 rows)
#define PB (NA * NRG)                // 864 proj blocks

typedef unsigned int u32;
typedef _Float16 f16;
typedef __attribute__((ext_vector_type(8))) _Float16 f16x8;
typedef __attribute__((ext_vector_type(4))) float f32x4;

union U4H8 { uint4 q; f16 h[8]; f16x8 v; };

__device__ __forceinline__ u32 packh(float a, float b) {
    union { f16 h[2]; u32 u; } c;
    c.h[0] = (f16)a; c.h[1] = (f16)b; return c.u;
}
__device__ __forceinline__ uint4 pack8h(const float* t) {
    uint4 m;
    m.x = packh(t[0], t[1]); m.y = packh(t[2], t[3]);
    m.z = packh(t[4], t[5]); m.w = packh(t[6], t[7]);
    return m;
}
__device__ __forceinline__ void acc8h(float* s, float v, uint4 g) {
    U4H8 c; c.q = g;
    #pragma unroll
    for (int i = 0; i < 8; ++i) s[i] += v * (float)c.h[i];
}

// ---------------- prep: pack cols(u16)+vals(f16), 16B per 4 nnz ----------------
__global__ __launch_bounds__(256)
void prep_cv_kernel(const int* __restrict__ cols, const float* __restrict__ vals,
                    uint4* __restrict__ cvq)
{
    const int q = blockIdx.x * 256 + threadIdx.x;
    if (q >= NNZ / 4) return;
    const int4   c = ((const int4*)cols)[q];
    const float4 v = ((const float4*)vals)[q];
    uint4 o;
    o.x = ((u32)c.x & 0xffffu) | ((u32)c.y << 16);
    o.y = ((u32)c.z & 0xffffu) | ((u32)c.w << 16);
    o.z = packh(v.x, v.y);
    o.w = packh(v.z, v.w);
    cvq[q] = o;
}

// ------- k=0: T0 = X channels [c0,c0+CC) -> fp16 slab; optional fused BN+ReLU ---
template<int CC, bool BN>
__global__ __launch_bounds__(256)
void tile_slab_kernel(const float* __restrict__ X, int C_in, int c0,
                      uint4* __restrict__ slab0, const float* __restrict__ bnp)
{
    constexpr int LPR = CC / 8;
    constexpr int RPB = 256 / LPR;
    const int tid = threadIdx.x;
    const int j = tid % LPR, rloc = tid / LPR;
    const int r = blockIdx.x * RPB + rloc;
    if (r >= MR) return;
    const int n = r % NN;
    const float* xp = X + (size_t)n * C_in + c0 + 8 * j;
    const float4 t0 = *(const float4*)xp;
    const float4 t1 = *(const float4*)(xp + 4);
    float t[8] = { t0.x, t0.y, t0.z, t0.w, t1.x, t1.y, t1.z, t1.w };
    if (BN) {
        const int ch = c0 + 8 * j;
        #pragma unroll
        for (int i = 0; i < 8; ++i) {
            const float v = t[i] * bnp[ch + i] + bnp[64 + ch + i];
            t[i] = v > 0.f ? v : 0.f;
        }
    }
    slab0[(size_t)r * LPR + j] = pack8h(t);
}

// ---------------- spmm: gather slab(k-1), carry slab(k-2), write slab(k) --------
template<int CC, bool CHEB>
__device__ __forceinline__
void spmm_body(const uint4* __restrict__ sp, const uint4* __restrict__ sc,
               uint4* __restrict__ sw, const uint4* __restrict__ cvq,
               uint4* cvl)
{
    constexpr int LPR = CC / 8;
    constexpr int RPB = 256 / LPR;
    const int tid = threadIdx.x;
    const int j = tid % LPR, rloc = tid / LPR;
    const int r0 = blockIdx.x * RPB;
    const int nrow = (MR - r0) < RPB ? (MR - r0) : RPB;
    for (int e = tid; e < nrow * 4; e += 256)
        cvl[e] = cvq[(size_t)r0 * 4 + e];
    __syncthreads();
    const int r = r0 + rloc;
    if (r >= MR) return;

    int c[16]; float v[16];
    #pragma unroll
    for (int q = 0; q < 4; ++q) {
        const uint4 cq = cvl[rloc * 4 + q];
        c[4 * q + 0] = cq.x & 0xffffu; c[4 * q + 1] = cq.x >> 16;
        c[4 * q + 2] = cq.y & 0xffffu; c[4 * q + 3] = cq.y >> 16;
        union { u32 u; f16 h[2]; } z, w_;
        z.u = cq.z; w_.u = cq.w;
        v[4 * q + 0] = (float)z.h[0]; v[4 * q + 1] = (float)z.h[1];
        v[4 * q + 2] = (float)w_.h[0]; v[4 * q + 3] = (float)w_.h[1];
    }
    float s[8] = {0.f, 0.f, 0.f, 0.f, 0.f, 0.f, 0.f, 0.f};
    #pragma unroll
    for (int d = 0; d < DEG; ++d)
        acc8h(s, v[d], sp[(size_t)c[d] * LPR + j]);
    float t[8];
    if (CHEB) {
        U4H8 p; p.q = sc[(size_t)r * LPR + j];
        #pragma unroll
        for (int i = 0; i < 8; ++i) t[i] = 2.f * s[i] - (float)p.h[i];
    } else {
        #pragma unroll
        for (int i = 0; i < 8; ++i) t[i] = s[i];
    }
    sw[(size_t)r * LPR + j] = pack8h(t);
}

template<int CC, bool CHEB>
__global__ __launch_bounds__(256)
void spmm_only_kernel(const uint4* __restrict__ sp, const uint4* __restrict__ sc,
                      uint4* __restrict__ sw, const uint4* __restrict__ cvq)
{
    constexpr int RPB = 256 / (CC / 8);
    __shared__ uint4 cvl[RPB * 4];
    spmm_body<CC, CHEB>(sp, sc, sw, cvq, cvl);
}

// ---- proj: part (+)= sum_{p<NPROJ} sum_{slices s} T[.., s] W[kbase+p][c0+s*64+..] ----
template<int SCC, int NPROJ, bool FIRSTP>
__device__ __forceinline__
void proj_body(int pb, const uint4* __restrict__ s0, const uint4* __restrict__ s1,
               const float* __restrict__ W, float* __restrict__ part,
               int C_in, int c0, int kbase, u32* WH, u32* WL)
{
    constexpr int LPRF   = SCC / 8;
    constexpr int SLICES = SCC >= 64 ? SCC / 64 : 1;
    constexpr int SCH    = SCC >= 64 ? 64 : SCC;
    constexpr int CCH    = SCH / 32;
    const int tid = threadIdx.x;
    const int l = tid & 63, w = tid >> 6;
    const int a = pb / NRG, rg = pb % NRG;
    const int rows0 = rg * 64;
    const int hi16 = l >> 4;

    const int arow = rows0 + w * 16 + (l & 15);
    const int arc  = arow < NN ? arow : NN - 1;
    const size_t abase = (size_t)(a * NN + arc) * LPRF;

    f32x4 acc[4];
    #pragma unroll
    for (int nt = 0; nt < 4; ++nt) {
        #pragma unroll
        for (int rr = 0; rr < 4; ++rr) {
            const int orow = rows0 + w * 16 + hi16 * 4 + rr;
            float vv = 0.f;
            if (!FIRSTP && orow < NN)
                vv = part[((size_t)a * NN + orow) * 64 + nt * 16 + (l & 15)];
            acc[nt][rr] = vv;
        }
    }

    #pragma unroll
    for (int p = 0; p < NPROJ; ++p) {
        const uint4* sl = (p == 0) ? s0 : s1;
        #pragma unroll
        for (int s = 0; s < SLICES; ++s) {
            const float* Wk = W + ((size_t)(kbase + p) * NA * C_in
                                   + (size_t)a * C_in + c0 + s * 64) * 64;
            if (p | s) __syncthreads();
            for (int e = tid; e < CCH * 1024; e += 256) {
                const int i2 = e & 3;
                const int ll = (e >> 2) & 63;
                const int nt = (e >> 8) & 3;
                const int h  = e >> 10;
                const int cc  = h * 32 + (ll >> 4) * 8 + 2 * i2;
                const int col = nt * 16 + (ll & 15);
                const float w0 = Wk[(size_t)cc * 64 + col];
                const float w1 = Wk[(size_t)(cc + 1) * 64 + col];
                const f16 h0 = (f16)w0, h1 = (f16)w1;
                union { f16 h[2]; u32 u; } ph, pl;
                ph.h[0] = h0; ph.h[1] = h1;
                pl.h[0] = (f16)(w0 - (float)h0); pl.h[1] = (f16)(w1 - (float)h1);
                WH[e] = ph.u; WL[e] = pl.u;
            }
            __syncthreads();
            #pragma unroll
            for (int h = 0; h < CCH; ++h) {
                U4H8 af; af.q = sl[abase + s * 8 + h * 4 + hi16];
                #pragma unroll
                for (int nt = 0; nt < 4; ++nt) {
                    const int be = ((h * 4 + nt) * 64 + l) * 4;
                    U4H8 bh, bl;
                    bh.q = *(const uint4*)&WH[be];
                    bl.q = *(const uint4*)&WL[be];
                    acc[nt] = __builtin_amdgcn_mfma_f32_16x16x32_f16(af.v, bh.v, acc[nt], 0, 0, 0);
                    acc[nt] = __builtin_amdgcn_mfma_f32_16x16x32_f16(af.v, bl.v, acc[nt], 0, 0, 0);
                }
            }
        }
    }

    #pragma unroll
    for (int nt = 0; nt < 4; ++nt) {
        #pragma unroll
        for (int rr = 0; rr < 4; ++rr) {
            const int orow = rows0 + w * 16 + hi16 * 4 + rr;
            if (orow < NN)
                part[((size_t)a * NN + orow) * 64 + nt * 16 + (l & 15)] = acc[nt][rr];
        }
    }
}

// ---------------- even step: spmm(k) + proj(k-2, k-1) ----------------
template<int CC, bool FIRSTP>
__global__ __launch_bounds__(256)
void step2_kernel(const uint4* __restrict__ sp, const uint4* __restrict__ sc,
                  uint4* __restrict__ sw, const uint4* __restrict__ cvq,
                  const float* __restrict__ W, float* __restrict__ part,
                  int C_in, int c0, int kbase, int NB)
{
    constexpr int RPB = 256 / (CC / 8);
    __shared__ uint4 cvl[RPB * 4];
    __shared__ u32 WH[2048];
    __shared__ u32 WL[2048];
    if ((int)blockIdx.x < NB)
        spmm_body<CC, true>(sp, sc, sw, cvq, cvl);
    else
        proj_body<CC, 2, FIRSTP>((int)blockIdx.x - NB, sc, sp, W, part, C_in, c0, kbase, WH, WL);
}

template<int CC>
__global__ __launch_bounds__(256)
void proj_final_kernel(const uint4* __restrict__ sl, const float* __restrict__ W,
                       float* __restrict__ part, int C_in, int c0, int kproj)
{
    __shared__ u32 WH[2048];
    __shared__ u32 WL[2048];
    proj_body<CC, 1, false>((int)blockIdx.x, sl, sl, W, part, C_in, c0, kproj, WH, WL);
}

// ---------------- BN helpers ----------------
__global__ void bn_reduce_kernel(const float* __restrict__ part, float* __restrict__ acc)
{
    const int e = blockIdx.x * blockDim.x + threadIdx.x;
    if (e >= NN * 64) return;
    float s = 0.f;
    #pragma unroll
    for (int a = 0; a < NA; ++a) s += part[(size_t)a * NN * 64 + e];
    acc[e] = s;
}

__global__ __launch_bounds__(256)
void bn_stats_kernel(const float* __restrict__ acc, const float* __restrict__ gamma,
                     const float* __restrict__ beta, float* __restrict__ bnp)
{
    const int h = blockIdx.x;
    float s = 0.f, sq = 0.f;
    for (int n = threadIdx.x; n < NN; n += 256) {
        const float v = acc[(size_t)n * 64 + h];
        s += v; sq += v * v;
    }
    __shared__ float ls[256], lq[256];
    ls[threadIdx.x] = s; lq[threadIdx.x] = sq;
    __syncthreads();
    for (int st = 128; st > 0; st >>= 1) {
        if (threadIdx.x < st) { ls[threadIdx.x] += ls[threadIdx.x + st]; lq[threadIdx.x] += lq[threadIdx.x + st]; }
        __syncthreads();
    }
    if (threadIdx.x == 0) {
        const float mean = ls[0] / (float)NN;
        const float var  = lq[0] / (float)NN - mean * mean;
        const float sc   = gamma[h] / sqrtf(var + BN_EPS);
        bnp[h]      = sc;
        bnp[64 + h] = beta[h] - mean * sc;
    }
}

__global__ void bn_apply_kernel(const float* __restrict__ acc, const float* __restrict__ bnp,
                                float* __restrict__ H)
{
    const int e = blockIdx.x * blockDim.x + threadIdx.x;
    if (e >= NN * 64) return;
    const int h = e & 63;
    const float v = acc[e] * bnp[h] + bnp[64 + h];
    H[e] = v > 0.f ? v : 0.f;
}

// ---------------- fc2: fp32 GEMM (+bias, relu), 4+4 split tiles ----------------
template<bool RELU>
__global__ __launch_bounds__(256)
void gemm_bias_kernel(const float* __restrict__ A, const float* __restrict__ B,
                      const float* __restrict__ bias, float* __restrict__ C,
                      int Mm, int Nn, int Kk)
{
    __shared__ float As[16][132];
    __shared__ float Bs[16][132];
    const int tx = threadIdx.x & 15, ty = threadIdx.x >> 4;
    const int m0 = blockIdx.y * 128, n0 = blockIdx.x * 128;
    const bool full = (m0 + 128 <= Mm) && (n0 + 128 <= Nn);
    float acc[8][8] = {};
    for (int k0 = 0; k0 < Kk; k0 += 16) {
        if (full) {
            #pragma unroll
            for (int e = threadIdx.x; e < 512; e += 256) {
                const int i = e >> 2, q = e & 3;
                const float4 a4 = *(const float4*)&A[(size_t)(m0 + i) * Kk + k0 + 4 * q];
                As[4 * q + 0][i] = a4.x; As[4 * q + 1][i] = a4.y;
                As[4 * q + 2][i] = a4.z; As[4 * q + 3][i] = a4.w;
            }
            #pragma unroll
            for (int e = threadIdx.x; e < 512; e += 256) {
                const int kk = e >> 5, q = e & 31;
                *(float4*)&Bs[kk][4 * q] = *(const float4*)&B[(size_t)(k0 + kk) * Nn + n0 + 4 * q];
            }
        } else {
            for (int e = threadIdx.x; e < 128 * 16; e += 256) {
                const int i = e >> 4, kk = e & 15;
                const int row = m0 + i;
                As[kk][i] = (row < Mm) ? A[(size_t)row * Kk + k0 + kk] : 0.f;
            }
            for (int e = threadIdx.x; e < 16 * 128; e += 256) {
                const int kk = e >> 7, jj = e & 127;
                const int col = n0 + jj;
                Bs[kk][jj] = (col < Nn) ? B[(size_t)(k0 + kk) * Nn + col] : 0.f;
            }
        }
        __syncthreads();
        #pragma unroll
        for (int kk = 0; kk < 16; ++kk) {
            float av[8], bv[8];
            *(float4*)&av[0] = *(const float4*)&As[kk][ty * 4];
            *(float4*)&av[4] = *(const float4*)&As[kk][64 + ty * 4];
            *(float4*)&bv[0] = *(const float4*)&Bs[kk][tx * 4];
            *(float4*)&bv[4] = *(const float4*)&Bs[kk][64 + tx * 4];
            #pragma unroll
            for (int i = 0; i < 8; ++i)
                #pragma unroll
                for (int jj = 0; jj < 8; ++jj)
                    acc[i][jj] += av[i] * bv[jj];
        }
        __syncthreads();
    }
    for (int i = 0; i < 8; ++i) {
        const int row = m0 + (i < 4 ? ty * 4 + i : 64 + ty * 4 + (i - 4));
        if (row >= Mm) continue;
        for (int jj = 0; jj < 8; ++jj) {
            const int col = n0 + (jj < 4 ? tx * 4 + jj : 64 + tx * 4 + (jj - 4));
            if (col >= Nn) continue;
            float v = acc[i][jj] + bias[col];
            if (RELU) v = fmaxf(v, 0.f);
            C[(size_t)row * Nn + col] = v;
        }
    }
}

// ---- prep: fc3_w -> transposed f16 hi/lo, K-MAJOR [k/8][col][8] ----
__global__ __launch_bounds__(256)
void w3_split_kernel(const float* __restrict__ W, f16* __restrict__ Wh, f16* __restrict__ Wl)
{
    __shared__ float t[64][65];
    const int tid = threadIdx.x;
    const int n0 = blockIdx.x * 64, k0 = blockIdx.y * 64;
    for (int e = tid; e < 64 * 64; e += 256) {
        const int kk = e >> 6, nn = e & 63;
        const int gn = n0 + nn;
        t[kk][nn] = (gn < NN) ? W[(size_t)(k0 + kk) * NN + gn] : 0.f;
    }
    __syncthreads();
    for (int e = tid; e < 64 * 8; e += 256) {
        const int nn = e >> 3, c8 = e & 7;
        const int gn = n0 + nn;
        if (gn >= NN) continue;
        const size_t ob = ((size_t)((k0 >> 3) + c8) * NN + gn) * 8;
        f16 vh[8], vl[8];
        #pragma unroll
        for (int i = 0; i < 8; ++i) {
            const float w = t[c8 * 8 + i][nn];
            const f16 h = (f16)w;
            vh[i] = h; vl[i] = (f16)(w - (float)h);
        }
        *(uint4*)&Wh[ob] = *(const uint4*)vh;
        *(uint4*)&Wl[ob] = *(const uint4*)vl;
    }
}

// ---- prep: f2 -> f16 hi/lo, K-MAJOR [k/8][row][8] ----
__global__ __launch_bounds__(256)
void f2_split_kernel(const float* __restrict__ f2, f16* __restrict__ Ah, f16* __restrict__ Al)
{
    const int row = blockIdx.x * 256 + threadIdx.x;
    const int c = blockIdx.y;                          // 0..31
    if (row >= NN) return;
    const float4 a0 = *(const float4*)&f2[(size_t)row * 256 + c * 8];
    const float4 a1 = *(const float4*)&f2[(size_t)row * 256 + c * 8 + 4];
    const float vv[8] = { a0.x, a0.y, a0.z, a0.w, a1.x, a1.y, a1.z, a1.w };
    f16 vh[8], vl[8];
    #pragma unroll
    for (int i = 0; i < 8; ++i) {
        const f16 h = (f16)vv[i];
        vh[i] = h; vl[i] = (f16)(vv[i] - (float)h);
    }
    const size_t ob = ((size_t)c * NN + row) * 8;
    *(uint4*)&Ah[ob] = *(const uint4*)vh;
    *(uint4*)&Al[ob] = *(const uint4*)vl;
}

// ---------------- fc3: k-major LDS-free f16-split MFMA GEMM (3 products) --------
__global__ __launch_bounds__(256)
void fc3_mfma_kernel(const f16* __restrict__ Ah, const f16* __restrict__ Al,
                     const f16* __restrict__ Bh, const f16* __restrict__ Bl,
                     const float* __restrict__ bias, float* __restrict__ C)
{
    const int tid = threadIdx.x, l = tid & 63, w = tid >> 6;
    const int wm = w >> 1, wn = w & 1, hi16 = l >> 4;
    const int m0 = blockIdx.y * 128, n0 = blockIdx.x * 128;

    size_t aoff[4], boff[4];
    #pragma unroll
    for (int mf = 0; mf < 4; ++mf) {
        int row = m0 + wm * 64 + mf * 16 + (l & 15);
        if (row > NN - 1) row = NN - 1;
        aoff[mf] = (size_t)row * 8;
    }
    #pragma unroll
    for (int nf = 0; nf < 4; ++nf) {
        int col = n0 + wn * 64 + nf * 16 + (l & 15);
        if (col > NN - 1) col = NN - 1;
        boff[nf] = (size_t)col * 8;
    }

    f32x4 acc[4][4];
    #pragma unroll
    for (int mf = 0; mf < 4; ++mf)
        #pragma unroll
        for (int nf = 0; nf < 4; ++nf)
            acc[mf][nf] = (f32x4){0.f, 0.f, 0.f, 0.f};

    for (int k0 = 0; k0 < 256; k0 += 32) {
        const size_t cb = (size_t)((k0 >> 3) + hi16) * NN * 8;
        f16x8 ah[4], al[4], bh[4], bl[4];
        #pragma unroll
        for (int mf = 0; mf < 4; ++mf) {
            ah[mf] = *(const f16x8*)(Ah + cb + aoff[mf]);
            al[mf] = *(const f16x8*)(Al + cb + aoff[mf]);
        }
        #pragma unroll
        for (int nf = 0; nf < 4; ++nf) {
            bh[nf] = *(const f16x8*)(Bh + cb + boff[nf]);
            bl[nf] = *(const f16x8*)(Bl + cb + boff[nf]);
        }
        #pragma unroll
        for (int mf = 0; mf < 4; ++mf)
            #pragma unroll
            for (int nf = 0; nf < 4; ++nf) {
                acc[mf][nf] = __builtin_amdgcn_mfma_f32_16x16x32_f16(ah[mf], bh[nf], acc[mf][nf], 0, 0, 0);
                acc[mf][nf] = __builtin_amdgcn_mfma_f32_16x16x32_f16(ah[mf], bl[nf], acc[mf][nf], 0, 0, 0);
                acc[mf][nf] = __builtin_amdgcn_mfma_f32_16x16x32_f16(al[mf], bh[nf], acc[mf][nf], 0, 0, 0);
            }
    }

    #pragma unroll
    for (int mf = 0; mf < 4; ++mf) {
        #pragma unroll
        for (int nf = 0; nf < 4; ++nf) {
            const int col = n0 + wn * 64 + nf * 16 + (l & 15);
            if (col >= NN) continue;
            const float bv = bias[col];
            #pragma unroll
            for (int rr = 0; rr < 4; ++rr) {
                const int row = m0 + wm * 64 + mf * 16 + hi16 * 4 + rr;
                if (row < NN)
                    C[(size_t)row * NN + col] = acc[mf][nf][rr] + bv;
            }
        }
    }
}

// ---------------- chunk driver (ring-3, proj every 2 k's) ----------------
template<int CC, bool BN>
static void run_chunk(bool first, const float* X, int C_in, int c0,
                      const uint4* cvq, const float* W, const float* bnp,
                      uint4* slabs, float* part, hipStream_t stream)
{
    constexpr int RPB = 256 / (CC / 8);
    const int NB = (MR + RPB - 1) / RPB;
    const size_t SLOT = (size_t)MR * (CC / 8);
    uint4* sl[3] = { slabs, slabs + SLOT, slabs + 2 * SLOT };

    tile_slab_kernel<CC, BN><<<NB, 256, 0, stream>>>(X, C_in, c0, sl[0], bnp);
    spmm_only_kernel<CC, false><<<NB, 256, 0, stream>>>(sl[0], sl[0], sl[1], cvq);   // k=1
    for (int k = 2; k < KC; ++k) {
        const int p = (k - 1) % 3, c = (k - 2) % 3, n = k % 3;
        if (k & 1) {
            spmm_only_kernel<CC, true><<<NB, 256, 0, stream>>>(sl[p], sl[c], sl[n], cvq);
        } else {
            if (first && k == 2)
                step2_kernel<CC, true ><<<NB + PB, 256, 0, stream>>>(
                    sl[p], sl[c], sl[n], cvq, W, part, C_in, c0, k - 2, NB);
            else
                step2_kernel<CC, false><<<NB + PB, 256, 0, stream>>>(
                    sl[p], sl[c], sl[n], cvq, W, part, C_in, c0, k - 2, NB);
        }
    }
    proj_final_kernel<CC><<<PB, 256, 0, stream>>>(sl[(KC - 1) % 3], W, part, C_in, c0, KC - 1);
}

extern "C" void kernel_launch(void* const* d_in, const int* in_sizes, int n_in,
                              void* d_out, int out_size, void* d_ws, size_t ws_size,
                              hipStream_t stream)
{
    (void)in_sizes; (void)n_in; (void)out_size; (void)ws_size;
    const float* x     = (const float*)d_in[0];
    const int*   cols  = (const int*)  d_in[2];
    const float* vals  = (const float*)d_in[3];
    const float* W1    = (const float*)d_in[4];
    const float* Wc    = (const float*)d_in[5];
    const float* gamma = (const float*)d_in[7];
    const float* beta  = (const float*)d_in[8];
    const float* fc2w  = (const float*)d_in[9];
    const float* fc2b  = (const float*)d_in[10];
    const float* fc3w  = (const float*)d_in[11];
    const float* fc3b  = (const float*)d_in[12];

    const size_t MT = (size_t)MR * 64;

    // slab ring lives in d_out (190 MB, fully rewritten by fc3 at the end):
    // CC=256 ring = 3 x MR x 512 B = 84.7 MB
    uint4* slabs = (uint4*)d_out;

    char* base = (char*)d_ws;
    size_t off = 0;
    uint4* cvq  = (uint4*)(base + off); off += (size_t)(NNZ / 4) * 16;   // 3.5 MB
    float* part = (float*)(base + off); off += MT * 4;                   // 14.1 MB
    float* acc  = (float*)(base + off); off += (size_t)NN * 64 * 4;
    float* H    = (float*)(base + off); off += (size_t)NN * 64 * 4;
    float* f2   = (float*)(base + off); off += (size_t)NN * 256 * 4;
    f16* f2h    = (f16*)(base + off);   off += (size_t)NN * 256 * 2;
    f16* f2l    = (f16*)(base + off);   off += (size_t)NN * 256 * 2;
    f16* W3h    = (f16*)(base + off);   off += (size_t)NN * 256 * 2;
    f16* W3l    = (f16*)(base + off);   off += (size_t)NN * 256 * 2;
    float* bnp  = (float*)(base + off);

    prep_cv_kernel<<<(NNZ / 4 + 255) / 256, 256, 0, stream>>>(cols, vals, cvq);
    w3_split_kernel<<<dim3(108, 4), 256, 0, stream>>>(fc3w, W3h, W3l);

    for (int li = 0; li < 6; ++li) {
        const int C_in = (li == 0) ? ND : 64;
        const float* W = (li == 0) ? W1 : Wc + (size_t)(li - 1) * KC * (NA * 64) * 64;

        if (li == 0) {
            // two wide CC=256 chains + 32-ch tail (slab ring in d_out)
            run_chunk<256, false>(true,  x, C_in, 0,   cvq, W, nullptr, slabs, part, stream);
            run_chunk<256, false>(false, x, C_in, 256, cvq, W, nullptr, slabs, part, stream);
            run_chunk<32,  false>(false, x, C_in, 512, cvq, W, nullptr, slabs, part, stream);
        } else {
            // BN(li-1) fused into tile: read acc + bnp
            run_chunk<64, true>(true, acc, C_in, 0, cvq, W, bnp, slabs, part, stream);
        }

        bn_reduce_kernel<<<(NN * 64 + 255) / 256, 256, 0, stream>>>(part, acc);
        bn_stats_kernel<<<64, 256, 0, stream>>>(acc, gamma + li * 64, beta + li * 64, bnp);
        if (li == 5)
            bn_apply_kernel<<<(NN * 64 + 255) / 256, 256, 0, stream>>>(acc, bnp, H);
    }

    gemm_bias_kernel<true><<<dim3(2, 54), 256, 0, stream>>>(H, fc2w, fc2b, f2, NN, 256, 64);
    f2_split_kernel<<<dim3(27, 32), 256, 0, stream>>>(f2, f2h, f2l);
    fc3_mfma_kernel<<<dim3(54, 54), 256, 0, stream>>>(f2h, f2l, W3h, W3l, fc3b, (float*)d_out);
}

// Round 14
// 3875.866 us; speedup vs baseline: 1.3574x; 1.0538x over previous
//
#include <hip/hip_runtime.h>
#include <cstdint>
#include <cstddef>

#define NN 6890
#define NA 8
#define KC 15
#define ND 544
#define MR (NA * NN)                 // 55120
#define DEG 16
#define NNZ (MR * DEG)
#define BN_EPS 1e-5f
#define NRG 108
#define PB (NA * NRG)                // 864 proj blocks
#define NB256 6890                   // 55120/8
#define NB32  862                    // ceil(55120/64)
#define NB64  1723                   // ceil(55120/32)

typedef unsigned int u32;
typedef _Float16 f16;
typedef __attribute__((ext_vector_type(8))) _Float16 f16x8;
typedef __attribute__((ext_vector_type(4))) _Float16 f16x4;
typedef __attribute__((ext_vector_type(4))) float f32x4;

union U4H8 { uint4 q; f16 h[8]; f16x8 v; };

struct Slabs4 { const uint4* s[4]; };

__device__ __forceinline__ u32 packh(float a, float b) {
    union { f16 h[2]; u32 u; } c;
    c.h[0] = (f16)a; c.h[1] = (f16)b; return c.u;
}
__device__ __forceinline__ uint4 pack8h(const float* t) {
    uint4 m;
    m.x = packh(t[0], t[1]); m.y = packh(t[2], t[3]);
    m.z = packh(t[4], t[5]); m.w = packh(t[6], t[7]);
    return m;
}
__device__ __forceinline__ void acc8h(float* s, float v, uint4 g) {
    U4H8 c; c.q = g;
    #pragma unroll
    for (int i = 0; i < 8; ++i) s[i] += v * (float)c.h[i];
}

// ---------------- prep: pack cols(u16)+vals(f16), 16B per 4 nnz ----------------
__global__ __launch_bounds__(256)
void prep_cv_kernel(const int* __restrict__ cols, const float* __restrict__ vals,
                    uint4* __restrict__ cvq)
{
    const int q = blockIdx.x * 256 + threadIdx.x;
    if (q >= NNZ / 4) return;
    const int4   c = ((const int4*)cols)[q];
    const float4 v = ((const float4*)vals)[q];
    uint4 o;
    o.x = ((u32)c.x & 0xffffu) | ((u32)c.y << 16);
    o.y = ((u32)c.z & 0xffffu) | ((u32)c.w << 16);
    o.z = packh(v.x, v.y);
    o.w = packh(v.z, v.w);
    cvq[q] = o;
}

// ---------------- tile body: X channels [c0,c0+CC) -> fp16 slab ----------------
template<int CC, bool BN>
__device__ __forceinline__
void tile_body(int bid, const float* __restrict__ X, int C_in, int c0,
               uint4* __restrict__ slab0, const float* __restrict__ bnp)
{
    constexpr int LPR = CC / 8;
    constexpr int RPB = 256 / LPR;
    const int tid = threadIdx.x;
    const int j = tid % LPR, rloc = tid / LPR;
    const int r = bid * RPB + rloc;
    if (r >= MR) return;
    const int n = r % NN;
    const float* xp = X + (size_t)n * C_in + c0 + 8 * j;
    const float4 t0 = *(const float4*)xp;
    const float4 t1 = *(const float4*)(xp + 4);
    float t[8] = { t0.x, t0.y, t0.z, t0.w, t1.x, t1.y, t1.z, t1.w };
    if (BN) {
        const int ch = c0 + 8 * j;
        #pragma unroll
        for (int i = 0; i < 8; ++i) {
            const float v = t[i] * bnp[ch + i] + bnp[64 + ch + i];
            t[i] = v > 0.f ? v : 0.f;
        }
    }
    slab0[(size_t)r * LPR + j] = pack8h(t);
}

__global__ __launch_bounds__(256)
void tile_l0_kernel(const float* __restrict__ X,
                    uint4* __restrict__ sA, uint4* __restrict__ sB,
                    uint4* __restrict__ sT)
{
    const int bid = blockIdx.x;
    if (bid < NB256)            tile_body<256, false>(bid, X, ND, 0, sA, nullptr);
    else if (bid < 2 * NB256)   tile_body<256, false>(bid - NB256, X, ND, 256, sB, nullptr);
    else                        tile_body<32,  false>(bid - 2 * NB256, X, ND, 512, sT, nullptr);
}

__global__ __launch_bounds__(256)
void tile64_bn_kernel(const float* __restrict__ X, uint4* __restrict__ slab0,
                      const float* __restrict__ bnp)
{
    tile_body<64, true>(blockIdx.x, X, 64, 0, slab0, bnp);
}

// ---------------- spmm body ----------------
template<int CC, bool CHEB>
__device__ __forceinline__
void spmm_body(int bid, const uint4* __restrict__ sp, const uint4* __restrict__ sc,
               uint4* __restrict__ sw, const uint4* __restrict__ cvq, uint4* cvl)
{
    constexpr int LPR = CC / 8;
    constexpr int RPB = 256 / LPR;
    const int tid = threadIdx.x;
    const int j = tid % LPR, rloc = tid / LPR;
    const int r0 = bid * RPB;
    const int nrow = (MR - r0) < RPB ? (MR - r0) : RPB;
    for (int e = tid; e < nrow * 4; e += 256)
        cvl[e] = cvq[(size_t)r0 * 4 + e];
    __syncthreads();
    const int r = r0 + rloc;
    if (r >= MR) return;

    int c[16]; float v[16];
    #pragma unroll
    for (int q = 0; q < 4; ++q) {
        const uint4 cq = cvl[rloc * 4 + q];
        c[4 * q + 0] = cq.x & 0xffffu; c[4 * q + 1] = cq.x >> 16;
        c[4 * q + 2] = cq.y & 0xffffu; c[4 * q + 3] = cq.y >> 16;
        union { u32 u; f16 h[2]; } z, w_;
        z.u = cq.z; w_.u = cq.w;
        v[4 * q + 0] = (float)z.h[0]; v[4 * q + 1] = (float)z.h[1];
        v[4 * q + 2] = (float)w_.h[0]; v[4 * q + 3] = (float)w_.h[1];
    }
    float s[8] = {0.f, 0.f, 0.f, 0.f, 0.f, 0.f, 0.f, 0.f};
    #pragma unroll
    for (int d = 0; d < DEG; ++d)
        acc8h(s, v[d], sp[(size_t)c[d] * LPR + j]);
    float t[8];
    if (CHEB) {
        U4H8 p; p.q = sc[(size_t)r * LPR + j];
        #pragma unroll
        for (int i = 0; i < 8; ++i) t[i] = 2.f * s[i] - (float)p.h[i];
    } else {
        #pragma unroll
        for (int i = 0; i < 8; ++i) t[i] = s[i];
    }
    sw[(size_t)r * LPR + j] = pack8h(t);
}

// ---------------- proj helpers ----------------
template<bool FIRSTP>
__device__ __forceinline__
void proj_ld(f32x4 (&acc)[4], const float* __restrict__ part, int a, int rows0,
             int l, int w)
{
    const int hi16 = l >> 4;
    #pragma unroll
    for (int nt = 0; nt < 4; ++nt)
        #pragma unroll
        for (int rr = 0; rr < 4; ++rr) {
            const int orow = rows0 + w * 16 + hi16 * 4 + rr;
            float vv = 0.f;
            if (!FIRSTP && orow < NN)
                vv = part[((size_t)a * NN + orow) * 64 + nt * 16 + (l & 15)];
            acc[nt][rr] = vv;
        }
}

__device__ __forceinline__
void proj_st(const f32x4 (&acc)[4], float* __restrict__ part, int a, int rows0,
             int l, int w)
{
    const int hi16 = l >> 4;
    #pragma unroll
    for (int nt = 0; nt < 4; ++nt)
        #pragma unroll
        for (int rr = 0; rr < 4; ++rr) {
            const int orow = rows0 + w * 16 + hi16 * 4 + rr;
            if (orow < NN)
                part[((size_t)a * NN + orow) * 64 + nt * 16 + (l & 15)] = acc[nt][rr];
        }
}

// accumulate sum_{p<NPROJ} sum_slices T[slab p][.., slice] * W[kbase+p][c0+s*64..]
// mfma_f32_16x16x32_f16; C/D col=l&15, row=(l>>4)*4+reg [m89-verified]
template<int SCC, int NPROJ>
__device__ __forceinline__
void proj_accum(int a, int rows0, int l, int w, Slabs4 sl,
                const float* __restrict__ W, int C_in, int c0, int kbase,
                u32* WH, u32* WL, f32x4 (&acc)[4], bool presync)
{
    constexpr int LPRF   = SCC / 8;
    constexpr int SLICES = SCC >= 64 ? SCC / 64 : 1;
    constexpr int SCH    = SCC >= 64 ? 64 : SCC;
    constexpr int CCH    = SCH / 32;
    const int tid = threadIdx.x;
    const int hi16 = l >> 4;
    const int arow = rows0 + w * 16 + (l & 15);
    const int arc  = arow < NN ? arow : NN - 1;
    const size_t abase = (size_t)(a * NN + arc) * LPRF;

    #pragma unroll
    for (int p = 0; p < NPROJ; ++p) {
        const uint4* slab = sl.s[p];
        #pragma unroll
        for (int s = 0; s < SLICES; ++s) {
            const float* Wk = W + ((size_t)(kbase + p) * NA * C_in
                                   + (size_t)a * C_in + c0 + s * 64) * 64;
            if (p | s) __syncthreads();
            else if (presync) __syncthreads();
            for (int e = tid; e < CCH * 1024; e += 256) {
                const int i2 = e & 3;
                const int ll = (e >> 2) & 63;
                const int nt = (e >> 8) & 3;
                const int h  = e >> 10;
                const int cc  = h * 32 + (ll >> 4) * 8 + 2 * i2;
                const int col = nt * 16 + (ll & 15);
                const float w0 = Wk[(size_t)cc * 64 + col];
                const float w1 = Wk[(size_t)(cc + 1) * 64 + col];
                const f16 h0 = (f16)w0, h1 = (f16)w1;
                union { f16 h[2]; u32 u; } ph, pl;
                ph.h[0] = h0; ph.h[1] = h1;
                pl.h[0] = (f16)(w0 - (float)h0); pl.h[1] = (f16)(w1 - (float)h1);
                WH[e] = ph.u; WL[e] = pl.u;
            }
            __syncthreads();
            #pragma unroll
            for (int h = 0; h < CCH; ++h) {
                U4H8 af; af.q = slab[abase + s * 8 + h * 4 + hi16];
                #pragma unroll
                for (int nt = 0; nt < 4; ++nt) {
                    const int be = ((h * 4 + nt) * 64 + l) * 4;
                    U4H8 bh, bl;
                    bh.q = *(const uint4*)&WH[be];
                    bl.q = *(const uint4*)&WL[be];
                    acc[nt] = __builtin_amdgcn_mfma_f32_16x16x32_f16(af.v, bh.v, acc[nt], 0, 0, 0);
                    acc[nt] = __builtin_amdgcn_mfma_f32_16x16x32_f16(af.v, bl.v, acc[nt], 0, 0, 0);
                }
            }
        }
    }
}

// ---------------- L0 kernels (multichain: 256 + 256 + 32 channels) ----------------
template<bool CHEB>
__global__ __launch_bounds__(256)
void spmm_l0_kernel(const uint4* __restrict__ sAp, const uint4* __restrict__ sAc, uint4* __restrict__ sAw,
                    const uint4* __restrict__ sBp, const uint4* __restrict__ sBc, uint4* __restrict__ sBw,
                    const uint4* __restrict__ sTp, const uint4* __restrict__ sTc, uint4* __restrict__ sTw,
                    const uint4* __restrict__ cvq)
{
    __shared__ uint4 cvl[256];
    const int bid = blockIdx.x;
    if (bid < NB256)          spmm_body<256, CHEB>(bid, sAp, sAc, sAw, cvq, cvl);
    else if (bid < 2 * NB256) spmm_body<256, CHEB>(bid - NB256, sBp, sBc, sBw, cvq, cvl);
    else                      spmm_body<32,  CHEB>(bid - 2 * NB256, sTp, sTc, sTw, cvq, cvl);
}

template<bool FIRSTP>
__global__ __launch_bounds__(256)
void step_l0_proj_kernel(const uint4* __restrict__ sAp, const uint4* __restrict__ sAc, uint4* __restrict__ sAw,
                         const uint4* __restrict__ sBp, const uint4* __restrict__ sBc, uint4* __restrict__ sBw,
                         const uint4* __restrict__ sTp, const uint4* __restrict__ sTc, uint4* __restrict__ sTw,
                         const uint4* __restrict__ cvq, const float* __restrict__ W,
                         float* __restrict__ part, int kbase)
{
    __shared__ uint4 cvl[256];
    __shared__ u32 WH[2048];
    __shared__ u32 WL[2048];
    const int bid = blockIdx.x;
    if (bid < NB256)          { spmm_body<256, true>(bid, sAp, sAc, sAw, cvq, cvl); return; }
    if (bid < 2 * NB256)      { spmm_body<256, true>(bid - NB256, sBp, sBc, sBw, cvq, cvl); return; }
    if (bid < 2 * NB256 + NB32) { spmm_body<32, true>(bid - 2 * NB256, sTp, sTc, sTw, cvq, cvl); return; }
    const int pb = bid - (2 * NB256 + NB32);
    const int l = threadIdx.x & 63, w = threadIdx.x >> 6;
    const int a = pb / NRG, rows0 = (pb % NRG) * 64;
    f32x4 acc[4];
    proj_ld<FIRSTP>(acc, part, a, rows0, l, w);
    Slabs4 sa; sa.s[0] = sAc; sa.s[1] = sAp;
    Slabs4 sb; sb.s[0] = sBc; sb.s[1] = sBp;
    Slabs4 st; st.s[0] = sTc; st.s[1] = sTp;
    proj_accum<256, 2>(a, rows0, l, w, sa, W, ND, 0,   kbase, WH, WL, acc, false);
    proj_accum<256, 2>(a, rows0, l, w, sb, W, ND, 256, kbase, WH, WL, acc, true);
    proj_accum<32,  2>(a, rows0, l, w, st, W, ND, 512, kbase, WH, WL, acc, true);
    proj_st(acc, part, a, rows0, l, w);
}

__global__ __launch_bounds__(256)
void proj_l0_final_kernel(const uint4* __restrict__ sA, const uint4* __restrict__ sB,
                          const uint4* __restrict__ sT, const float* __restrict__ W,
                          float* __restrict__ part, int kbase)
{
    __shared__ u32 WH[2048];
    __shared__ u32 WL[2048];
    const int pb = blockIdx.x;
    const int l = threadIdx.x & 63, w = threadIdx.x >> 6;
    const int a = pb / NRG, rows0 = (pb % NRG) * 64;
    f32x4 acc[4];
    proj_ld<false>(acc, part, a, rows0, l, w);
    Slabs4 sa; sa.s[0] = sA;
    Slabs4 sb; sb.s[0] = sB;
    Slabs4 st; st.s[0] = sT;
    proj_accum<256, 1>(a, rows0, l, w, sa, W, ND, 0,   kbase, WH, WL, acc, false);
    proj_accum<256, 1>(a, rows0, l, w, sb, W, ND, 256, kbase, WH, WL, acc, true);
    proj_accum<32,  1>(a, rows0, l, w, st, W, ND, 512, kbase, WH, WL, acc, true);
    proj_st(acc, part, a, rows0, l, w);
}

// ---------------- L1-5 kernels (CC=64, ring-5, NPROJ=4) ----------------
template<bool CHEB>
__global__ __launch_bounds__(256)
void spmm64_kernel(const uint4* __restrict__ sp, const uint4* __restrict__ sc,
                   uint4* __restrict__ sw, const uint4* __restrict__ cvq)
{
    __shared__ uint4 cvl[128];
    spmm_body<64, CHEB>(blockIdx.x, sp, sc, sw, cvq, cvl);
}

template<bool FIRSTP>
__global__ __launch_bounds__(256)
void step64_proj4_kernel(const uint4* __restrict__ sp, const uint4* __restrict__ sc,
                         uint4* __restrict__ sw, Slabs4 prj,
                         const uint4* __restrict__ cvq, const float* __restrict__ W,
                         float* __restrict__ part, int kbase)
{
    __shared__ uint4 cvl[128];
    __shared__ u32 WH[2048];
    __shared__ u32 WL[2048];
    const int bid = blockIdx.x;
    if (bid < NB64) { spmm_body<64, true>(bid, sp, sc, sw, cvq, cvl); return; }
    const int pb = bid - NB64;
    const int l = threadIdx.x & 63, w = threadIdx.x >> 6;
    const int a = pb / NRG, rows0 = (pb % NRG) * 64;
    f32x4 acc[4];
    proj_ld<FIRSTP>(acc, part, a, rows0, l, w);
    proj_accum<64, 4>(a, rows0, l, w, prj, W, 64, 0, kbase, WH, WL, acc, false);
    proj_st(acc, part, a, rows0, l, w);
}

__global__ __launch_bounds__(256)
void proj64_final_kernel(Slabs4 prj, const float* __restrict__ W,
                         float* __restrict__ part, int kbase)
{
    __shared__ u32 WH[2048];
    __shared__ u32 WL[2048];
    const int pb = blockIdx.x;
    const int l = threadIdx.x & 63, w = threadIdx.x >> 6;
    const int a = pb / NRG, rows0 = (pb % NRG) * 64;
    f32x4 acc[4];
    proj_ld<false>(acc, part, a, rows0, l, w);
    proj_accum<64, 3>(a, rows0, l, w, prj, W, 64, 0, kbase, WH, WL, acc, false);
    proj_st(acc, part, a, rows0, l, w);
}

// ---------------- BN helpers ----------------
__global__ void bn_reduce_kernel(const float* __restrict__ part, float* __restrict__ acc)
{
    const int e = blockIdx.x * blockDim.x + threadIdx.x;
    if (e >= NN * 64) return;
    float s = 0.f;
    #pragma unroll
    for (int a = 0; a < NA; ++a) s += part[(size_t)a * NN * 64 + e];
    acc[e] = s;
}

__global__ __launch_bounds__(256)
void bn_stats_kernel(const float* __restrict__ acc, const float* __restrict__ gamma,
                     const float* __restrict__ beta, float* __restrict__ bnp)
{
    const int h = blockIdx.x;
    float s = 0.f, sq = 0.f;
    for (int n = threadIdx.x; n < NN; n += 256) {
        const float v = acc[(size_t)n * 64 + h];
        s += v; sq += v * v;
    }
    __shared__ float ls[256], lq[256];
    ls[threadIdx.x] = s; lq[threadIdx.x] = sq;
    __syncthreads();
    for (int st = 128; st > 0; st >>= 1) {
        if (threadIdx.x < st) { ls[threadIdx.x] += ls[threadIdx.x + st]; lq[threadIdx.x] += lq[threadIdx.x + st]; }
        __syncthreads();
    }
    if (threadIdx.x == 0) {
        const float mean = ls[0] / (float)NN;
        const float var  = lq[0] / (float)NN - mean * mean;
        const float sc   = gamma[h] / sqrtf(var + BN_EPS);
        bnp[h]      = sc;
        bnp[64 + h] = beta[h] - mean * sc;
    }
}

__global__ void bn_apply_kernel(const float* __restrict__ acc, const float* __restrict__ bnp,
                                float* __restrict__ H)
{
    const int e = blockIdx.x * blockDim.x + threadIdx.x;
    if (e >= NN * 64) return;
    const int h = e & 63;
    const float v = acc[e] * bnp[h] + bnp[64 + h];
    H[e] = v > 0.f ? v : 0.f;
}

// ------- fc2: fp32 GEMM + bias + relu, writes f16 hi/lo k-major directly -------
__global__ __launch_bounds__(256)
void fc2_kernel(const float* __restrict__ A, const float* __restrict__ B,
                const float* __restrict__ bias,
                f16* __restrict__ Oh, f16* __restrict__ Ol)
{
    constexpr int Kk = 64, Nn = 256;
    __shared__ float As[16][132];
    __shared__ float Bs[16][132];
    const int tx = threadIdx.x & 15, ty = threadIdx.x >> 4;
    const int m0 = blockIdx.y * 128, n0 = blockIdx.x * 128;
    const bool full = (m0 + 128 <= NN);
    float acc[8][8] = {};
    for (int k0 = 0; k0 < Kk; k0 += 16) {
        if (full) {
            #pragma unroll
            for (int e = threadIdx.x; e < 512; e += 256) {
                const int i = e >> 2, q = e & 3;
                const float4 a4 = *(const float4*)&A[(size_t)(m0 + i) * Kk + k0 + 4 * q];
                As[4 * q + 0][i] = a4.x; As[4 * q + 1][i] = a4.y;
                As[4 * q + 2][i] = a4.z; As[4 * q + 3][i] = a4.w;
            }
        } else {
            for (int e = threadIdx.x; e < 128 * 16; e += 256) {
                const int i = e >> 4, kk = e & 15;
                const int row = m0 + i;
                As[kk][i] = (row < NN) ? A[(size_t)row * Kk + k0 + kk] : 0.f;
            }
        }
        #pragma unroll
        for (int e = threadIdx.x; e < 512; e += 256) {
            const int kk = e >> 5, q = e & 31;
            *(float4*)&Bs[kk][4 * q] = *(const float4*)&B[(size_t)(k0 + kk) * Nn + n0 + 4 * q];
        }
        __syncthreads();
        #pragma unroll
        for (int kk = 0; kk < 16; ++kk) {
            float av[8], bv[8];
            *(float4*)&av[0] = *(const float4*)&As[kk][ty * 4];
            *(float4*)&av[4] = *(const float4*)&As[kk][64 + ty * 4];
            *(float4*)&bv[0] = *(const float4*)&Bs[kk][tx * 4];
            *(float4*)&bv[4] = *(const float4*)&Bs[kk][64 + tx * 4];
            #pragma unroll
            for (int i = 0; i < 8; ++i)
                #pragma unroll
                for (int jj = 0; jj < 8; ++jj)
                    acc[i][jj] += av[i] * bv[jj];
        }
        __syncthreads();
    }
    #pragma unroll
    for (int i = 0; i < 8; ++i) {
        const int row = m0 + (i < 4 ? ty * 4 + i : 64 + ty * 4 + (i - 4));
        if (row >= NN) continue;
        #pragma unroll
        for (int g = 0; g < 2; ++g) {
            const int colg = n0 + (g ? 64 : 0) + tx * 4;
            f16x4 vh, vl;
            #pragma unroll
            for (int jj = 0; jj < 4; ++jj) {
                float v = acc[i][g * 4 + jj] + bias[colg + jj];
                v = fmaxf(v, 0.f);
                const f16 h = (f16)v;
                vh[jj] = h; vl[jj] = (f16)(v - (float)h);
            }
            const size_t ob = ((size_t)(colg >> 3) * NN + row) * 8 + (colg & 7);
            *(f16x4*)&Oh[ob] = vh;
            *(f16x4*)&Ol[ob] = vl;
        }
    }
}

// ---- prep: fc3_w -> transposed f16 hi/lo, K-MAJOR [k/8][col][8] ----
__global__ __launch_bounds__(256)
void w3_split_kernel(const float* __restrict__ W, f16* __restrict__ Wh, f16* __restrict__ Wl)
{
    __shared__ float t[64][65];
    const int tid = threadIdx.x;
    const int n0 = blockIdx.x * 64, k0 = blockIdx.y * 64;
    for (int e = tid; e < 64 * 64; e += 256) {
        const int kk = e >> 6, nn = e & 63;
        const int gn = n0 + nn;
        t[kk][nn] = (gn < NN) ? W[(size_t)(k0 + kk) * NN + gn] : 0.f;
    }
    __syncthreads();
    for (int e = tid; e < 64 * 8; e += 256) {
        const int nn = e >> 3, c8 = e & 7;
        const int gn = n0 + nn;
        if (gn >= NN) continue;
        const size_t ob = ((size_t)((k0 >> 3) + c8) * NN + gn) * 8;
        f16 vh[8], vl[8];
        #pragma unroll
        for (int i = 0; i < 8; ++i) {
            const float w = t[c8 * 8 + i][nn];
            const f16 h = (f16)w;
            vh[i] = h; vl[i] = (f16)(w - (float)h);
        }
        *(uint4*)&Wh[ob] = *(const uint4*)vh;
        *(uint4*)&Wl[ob] = *(const uint4*)vl;
    }
}

// ---- fc3: k-major LDS-free f16-split MFMA GEMM, XCD-chunked swizzle ----
__global__ __launch_bounds__(256)
void fc3_mfma_kernel(const f16* __restrict__ Ah, const f16* __restrict__ Al,
                     const f16* __restrict__ Bh, const f16* __restrict__ Bl,
                     const float* __restrict__ bias, float* __restrict__ C)
{
    // bijective XCD swizzle (m204): nwg=2916, q=364, r=4; then 9-col bands
    const int o = blockIdx.x;
    const int xcd = o & 7, jj0 = o >> 3;
    const int wg = (xcd < 4 ? xcd * 365 : 4 * 365 + (xcd - 4) * 364) + jj0;
    const int band = wg / 486, inb = wg % 486;
    const int mt = inb / 9, nt = band * 9 + inb % 9;
    const int m0 = mt * 128, n0 = nt * 128;

    const int tid = threadIdx.x, l = tid & 63, w = tid >> 6;
    const int wm = w >> 1, wn = w & 1, hi16 = l >> 4;

    size_t aoff[4], boff[4];
    #pragma unroll
    for (int mf = 0; mf < 4; ++mf) {
        int row = m0 + wm * 64 + mf * 16 + (l & 15);
        if (row > NN - 1) row = NN - 1;
        aoff[mf] = (size_t)row * 8;
    }
    #pragma unroll
    for (int nf = 0; nf < 4; ++nf) {
        int col = n0 + wn * 64 + nf * 16 + (l & 15);
        if (col > NN - 1) col = NN - 1;
        boff[nf] = (size_t)col * 8;
    }

    f32x4 acc[4][4];
    #pragma unroll
    for (int mf = 0; mf < 4; ++mf)
        #pragma unroll
        for (int nf = 0; nf < 4; ++nf)
            acc[mf][nf] = (f32x4){0.f, 0.f, 0.f, 0.f};

    for (int k0 = 0; k0 < 256; k0 += 32) {
        const size_t cb = (size_t)((k0 >> 3) + hi16) * NN * 8;
        f16x8 ah[4], al[4], bh[4], bl[4];
        #pragma unroll
        for (int mf = 0; mf < 4; ++mf) {
            ah[mf] = *(const f16x8*)(Ah + cb + aoff[mf]);
            al[mf] = *(const f16x8*)(Al + cb + aoff[mf]);
        }
        #pragma unroll
        for (int nf = 0; nf < 4; ++nf) {
            bh[nf] = *(const f16x8*)(Bh + cb + boff[nf]);
            bl[nf] = *(const f16x8*)(Bl + cb + boff[nf]);
        }
        #pragma unroll
        for (int mf = 0; mf < 4; ++mf)
            #pragma unroll
            for (int nf = 0; nf < 4; ++nf) {
                acc[mf][nf] = __builtin_amdgcn_mfma_f32_16x16x32_f16(ah[mf], bh[nf], acc[mf][nf], 0, 0, 0);
                acc[mf][nf] = __builtin_amdgcn_mfma_f32_16x16x32_f16(ah[mf], bl[nf], acc[mf][nf], 0, 0, 0);
                acc[mf][nf] = __builtin_amdgcn_mfma_f32_16x16x32_f16(al[mf], bh[nf], acc[mf][nf], 0, 0, 0);
            }
    }

    #pragma unroll
    for (int mf = 0; mf < 4; ++mf) {
        #pragma unroll
        for (int nf = 0; nf < 4; ++nf) {
            const int col = n0 + wn * 64 + nf * 16 + (l & 15);
            if (col >= NN) continue;
            const float bv = bias[col];
            #pragma unroll
            for (int rr = 0; rr < 4; ++rr) {
                const int row = m0 + wm * 64 + mf * 16 + hi16 * 4 + rr;
                if (row < NN)
                    C[(size_t)row * NN + col] = acc[mf][nf][rr] + bv;
            }
        }
    }
}

extern "C" void kernel_launch(void* const* d_in, const int* in_sizes, int n_in,
                              void* d_out, int out_size, void* d_ws, size_t ws_size,
                              hipStream_t stream)
{
    (void)in_sizes; (void)n_in; (void)out_size; (void)ws_size;
    const float* x     = (const float*)d_in[0];
    const int*   cols  = (const int*)  d_in[2];
    const float* vals  = (const float*)d_in[3];
    const float* W1    = (const float*)d_in[4];
    const float* Wc    = (const float*)d_in[5];
    const float* gamma = (const float*)d_in[7];
    const float* beta  = (const float*)d_in[8];
    const float* fc2w  = (const float*)d_in[9];
    const float* fc2b  = (const float*)d_in[10];
    const float* fc3w  = (const float*)d_in[11];
    const float* fc3b  = (const float*)d_in[12];

    const size_t MT = (size_t)MR * 64;

    // L0 slab rings live in d_out (190 MB, fully rewritten by fc3):
    // chainA ring-3 @ CC=256 (84.7 MB), chainB ring-3 (84.7 MB), tail ring-3 @ CC=32 (10.6 MB)
    const size_t SL256 = (size_t)MR * 32;     // uint4 per CC=256 slab
    const size_t SL32  = (size_t)MR * 4;      // uint4 per CC=32 slab
    uint4* ringA = (uint4*)d_out;
    uint4* ringB = ringA + 3 * SL256;
    uint4* ringT = ringB + 3 * SL256;
    auto slA = [&](int k) { return ringA + (size_t)(k % 3) * SL256; };
    auto slB = [&](int k) { return ringB + (size_t)(k % 3) * SL256; };
    auto slT = [&](int k) { return ringT + (size_t)(k % 3) * SL32; };

    char* base = (char*)d_ws;
    size_t off = 0;
    uint4* cvq  = (uint4*)(base + off); off += (size_t)(NNZ / 4) * 16;   // 3.5 MB
    uint4* ring5 = (uint4*)(base + off); off += 5 * (size_t)MR * 8 * 16; // 35.3 MB (CC=64 ring-5)
    float* part = (float*)(base + off); off += MT * 4;                   // 14.1 MB
    float* acc  = (float*)(base + off); off += (size_t)NN * 64 * 4;
    float* H    = (float*)(base + off); off += (size_t)NN * 64 * 4;
    f16* f2h    = (f16*)(base + off);   off += (size_t)NN * 256 * 2;
    f16* f2l    = (f16*)(base + off);   off += (size_t)NN * 256 * 2;
    f16* W3h    = (f16*)(base + off);   off += (size_t)NN * 256 * 2;
    f16* W3l    = (f16*)(base + off);   off += (size_t)NN * 256 * 2;
    float* bnp  = (float*)(base + off);
    const size_t SL64 = (size_t)MR * 8;
    auto sl5 = [&](int k) { return ring5 + (size_t)(k % 5) * SL64; };

    prep_cv_kernel<<<(NNZ / 4 + 255) / 256, 256, 0, stream>>>(cols, vals, cvq);
    w3_split_kernel<<<dim3(108, 4), 256, 0, stream>>>(fc3w, W3h, W3l);

    // ---------------- layer 0 (multichain) ----------------
    {
        const float* W = W1;
        tile_l0_kernel<<<2 * NB256 + NB32, 256, 0, stream>>>(x, slA(0), slB(0), slT(0));
        spmm_l0_kernel<false><<<2 * NB256 + NB32, 256, 0, stream>>>(
            slA(0), slA(0), slA(1), slB(0), slB(0), slB(1), slT(0), slT(0), slT(1), cvq);
        for (int k = 2; k < KC; ++k) {
            if (k & 1) {
                spmm_l0_kernel<true><<<2 * NB256 + NB32, 256, 0, stream>>>(
                    slA(k - 1), slA(k - 2), slA(k), slB(k - 1), slB(k - 2), slB(k),
                    slT(k - 1), slT(k - 2), slT(k), cvq);
            } else if (k == 2) {
                step_l0_proj_kernel<true><<<2 * NB256 + NB32 + PB, 256, 0, stream>>>(
                    slA(k - 1), slA(k - 2), slA(k), slB(k - 1), slB(k - 2), slB(k),
                    slT(k - 1), slT(k - 2), slT(k), cvq, W, part, k - 2);
            } else {
                step_l0_proj_kernel<false><<<2 * NB256 + NB32 + PB, 256, 0, stream>>>(
                    slA(k - 1), slA(k - 2), slA(k), slB(k - 1), slB(k - 2), slB(k),
                    slT(k - 1), slT(k - 2), slT(k), cvq, W, part, k - 2);
            }
        }
        proj_l0_final_kernel<<<PB, 256, 0, stream>>>(slA(14), slB(14), slT(14), W, part, 14);
        bn_reduce_kernel<<<(NN * 64 + 255) / 256, 256, 0, stream>>>(part, acc);
        bn_stats_kernel<<<64, 256, 0, stream>>>(acc, gamma, beta, bnp);
    }

    // ---------------- layers 1..5 (CC=64, ring-5, NPROJ=4) ----------------
    for (int li = 1; li < 6; ++li) {
        const float* W = Wc + (size_t)(li - 1) * KC * (NA * 64) * 64;
        tile64_bn_kernel<<<NB64, 256, 0, stream>>>(acc, sl5(0), bnp);
        spmm64_kernel<false><<<NB64, 256, 0, stream>>>(sl5(0), sl5(0), sl5(1), cvq);
        for (int k = 2; k < KC; ++k) {
            if (k == 4 || k == 8 || k == 12) {
                Slabs4 prj;
                prj.s[0] = sl5(k - 4); prj.s[1] = sl5(k - 3);
                prj.s[2] = sl5(k - 2); prj.s[3] = sl5(k - 1);
                if (k == 4)
                    step64_proj4_kernel<true ><<<NB64 + PB, 256, 0, stream>>>(
                        sl5(k - 1), sl5(k - 2), sl5(k), prj, cvq, W, part, k - 4);
                else
                    step64_proj4_kernel<false><<<NB64 + PB, 256, 0, stream>>>(
                        sl5(k - 1), sl5(k - 2), sl5(k), prj, cvq, W, part, k - 4);
            } else {
                spmm64_kernel<true><<<NB64, 256, 0, stream>>>(sl5(k - 1), sl5(k - 2), sl5(k), cvq);
            }
        }
        Slabs4 prjf;
        prjf.s[0] = sl5(12); prjf.s[1] = sl5(13); prjf.s[2] = sl5(14); prjf.s[3] = sl5(14);
        proj64_final_kernel<<<PB, 256, 0, stream>>>(prjf, W, part, 12);
        bn_reduce_kernel<<<(NN * 64 + 255) / 256, 256, 0, stream>>>(part, acc);
        bn_stats_kernel<<<64, 256, 0, stream>>>(acc, gamma + li * 64, beta + li * 64, bnp);
    }

    bn_apply_kernel<<<(NN * 64 + 255) / 256, 256, 0, stream>>>(acc, bnp, H);
    fc2_kernel<<<dim3(2, 54), 256, 0, stream>>>(H, fc2w, fc2b, f2h, f2l);
    fc3_mfma_kernel<<<2916, 256, 0, stream>>>(f2h, f2l, W3h, W3l, fc3b, (float*)d_out);
}